// Round 1
// baseline (60177.649 us; speedup 1.0000x reference)
//
#include <hip/hip_runtime.h>
#include <math.h>

#define HW 3136
#define WIDTH 56
#define CC 256
#define BB 4
#define RCH 32

// ---------------------------------------------------------------------------
// Generic 1x1-conv GEMM: out[b,co,i] = sum_c w[co*Cin+c] * in[b,c,i] (+res)
// grid: (Cout/16, HW/64, B), block 256 = (16 i-lanes) x (16 co-lanes)
// ---------------------------------------------------------------------------
__global__ void gemm1x1(const float* __restrict__ in, const float* __restrict__ w,
                        const float* __restrict__ res, float* __restrict__ out,
                        int Cin, int Cout) {
    const int tx = threadIdx.x & 15;   // i within tile (x4 unroll)
    const int ty = threadIdx.x >> 4;   // co within tile
    const int i0 = blockIdx.y * 64;
    const int co0 = blockIdx.x * 16;
    const int b = blockIdx.z;

    __shared__ float xs[32][64];
    __shared__ float wsl[16][33];

    float acc[4] = {0.f, 0.f, 0.f, 0.f};
    const float* inb = in + (size_t)b * Cin * HW;

    for (int c0 = 0; c0 < Cin; c0 += 32) {
        #pragma unroll
        for (int k = 0; k < 8; ++k) {
            int e = threadIdx.x + k * 256;
            int r = e >> 6, col = e & 63;
            xs[r][col] = inb[(size_t)(c0 + r) * HW + i0 + col];
        }
        #pragma unroll
        for (int k = 0; k < 2; ++k) {
            int e = threadIdx.x + k * 256;
            int r = e >> 5, col = e & 31;
            wsl[r][col] = w[(size_t)(co0 + r) * Cin + c0 + col];
        }
        __syncthreads();
        #pragma unroll
        for (int c = 0; c < 32; ++c) {
            float wv = wsl[ty][c];
            #pragma unroll
            for (int u = 0; u < 4; ++u)
                acc[u] += wv * xs[c][tx + 16 * u];
        }
        __syncthreads();
    }

    size_t obase = ((size_t)b * Cout + co0 + ty) * HW + i0 + tx;
    if (res) {
        #pragma unroll
        for (int u = 0; u < 4; ++u)
            out[obase + 16 * u] = acc[u] + res[obase + 16 * u];
    } else {
        #pragma unroll
        for (int u = 0; u < 4; ++u)
            out[obase + 16 * u] = acc[u];
    }
}

// ---------------------------------------------------------------------------
// Direct KxK conv producing q[b, r(32), hw]. grid: (ceil(HW/256), B), block 256
// Weights staged in LDS in [c'][tap][r] order (r-broadcast reads).
// ---------------------------------------------------------------------------
template <int KS>
__global__ void qconv(const float* __restrict__ x, const float* __restrict__ w,
                      float* __restrict__ q) {
    constexpr int P = (KS - 1) / 2;
    constexpr int KT = KS * KS;
    const int b = blockIdx.y;
    const int i = blockIdx.x * 256 + threadIdx.x;
    const int y = i / WIDTH, xc = i % WIDTH;
    const bool valid = (i < HW);

    __shared__ float wl[8][KT][32];

    float acc[32];
    #pragma unroll
    for (int r = 0; r < 32; ++r) acc[r] = 0.f;

    for (int c0 = 0; c0 < CC; c0 += 8) {
        for (int e = threadIdx.x; e < 8 * KT * 32; e += 256) {
            int r = e & 31;
            int ct = e >> 5;
            int t = ct % KT, cp = ct / KT;
            wl[cp][t][r] = w[((size_t)(r << 8) + c0 + cp) * KT + t];
        }
        __syncthreads();
        if (valid) {
            for (int cp = 0; cp < 8; ++cp) {
                const float* xr = x + ((size_t)b * CC + c0 + cp) * HW;
                for (int t = 0; t < KT; ++t) {
                    int dy = t / KS - P, dx = t % KS - P;
                    int yy = y + dy, xx = xc + dx;
                    float xv = (yy >= 0 && yy < WIDTH && xx >= 0 && xx < WIDTH)
                                   ? xr[yy * WIDTH + xx] : 0.f;
                    #pragma unroll
                    for (int r = 0; r < 32; ++r) acc[r] += wl[cp][t][r] * xv;
                }
            }
        }
        __syncthreads();
    }
    if (valid) {
        #pragma unroll
        for (int r = 0; r < 32; ++r)
            q[((size_t)b * RCH + r) * HW + i] = acc[r];
    }
}

// ---------------------------------------------------------------------------
// Flash attention over one branch g: att[b, c, i] = sum_j v[c,j] softmax_j(q_i.k_j*scale)
// grid: (HW/32, B, 4 branches), block 256 (4 waves).
// Wave w owns query rows w*8..w*8+7 for scores; PV threads: i=t%32, cgroup=t/32.
// ---------------------------------------------------------------------------
__global__ void flashattn(const float* __restrict__ Q, const float* __restrict__ K,
                          const float* __restrict__ V, float* __restrict__ ATT) {
    const int b = blockIdx.y, g = blockIdx.z;
    const int i0 = blockIdx.x * 32;
    const float scale = 0.17677669529663687f;  // 1/sqrt(32)

    __shared__ float ql[32][33];                  // [r][i]
    __shared__ float kl[32][64];                  // [r][j]
    __shared__ __align__(16) float pl[32][64];    // [i][j]
    __shared__ float ml[32], ll[32], al[32];

    const int lane = threadIdx.x & 63;
    const int wv = threadIdx.x >> 6;

    const float* Qg = Q + ((size_t)(g * BB + b) * RCH) * HW;
    const float* Kb = K + (size_t)b * RCH * HW;

    // load q tile [32r][32i]
    #pragma unroll
    for (int k = 0; k < 4; ++k) {
        int e = threadIdx.x + k * 256;
        int r = e >> 5, ii = e & 31;
        ql[r][ii] = Qg[(size_t)r * HW + i0 + ii];
    }
    if (threadIdx.x < 32) { ml[threadIdx.x] = -1e30f; ll[threadIdx.x] = 0.f; }

    float o[32];
    #pragma unroll
    for (int cc = 0; cc < 32; ++cc) o[cc] = 0.f;

    __syncthreads();

    for (int jt = 0; jt < HW / 64; ++jt) {
        const int j0 = jt * 64;
        // K tile
        #pragma unroll
        for (int k = 0; k < 8; ++k) {
            int e = threadIdx.x + k * 256;
            int r = e >> 6, j = e & 63;
            kl[r][j] = Kb[(size_t)r * HW + j0 + j];
        }
        __syncthreads();  // k ready; prev-iter PV done (pl safe to overwrite)

        // scores + online softmax (wave-owned rows)
        #pragma unroll
        for (int ii = 0; ii < 8; ++ii) {
            const int i = wv * 8 + ii;
            float s = 0.f;
            #pragma unroll
            for (int r = 0; r < 32; ++r) s += ql[r][i] * kl[r][lane];
            s *= scale;
            float mx = s;
            #pragma unroll
            for (int off = 1; off < 64; off <<= 1) mx = fmaxf(mx, __shfl_xor(mx, off));
            float m_old = ml[i];
            float m_new = fmaxf(m_old, mx);
            float p = __expf(s - m_new);
            float sm = p;
            #pragma unroll
            for (int off = 1; off < 64; off <<= 1) sm += __shfl_xor(sm, off);
            pl[i][lane] = p;
            if (lane == 0) {
                float a = __expf(m_old - m_new);
                al[i] = a;
                ml[i] = m_new;
                ll[i] = ll[i] * a + sm;
            }
        }
        __syncthreads();  // p/alpha ready

        // PV: o[c,i] = o*alpha + sum_j v[c,j] * p[i,j]
        {
            const int i = threadIdx.x & 31;
            const int cg = threadIdx.x >> 5;
            const float a = al[i];
            #pragma unroll
            for (int cc = 0; cc < 32; ++cc) o[cc] *= a;
            const float* vb = V + ((size_t)b * CC + cg * 32) * HW + j0;
            const float4* pr = (const float4*)(&pl[i][0]);
            #pragma unroll
            for (int q4 = 0; q4 < 16; ++q4) {
                const float4 p4 = pr[q4];
                #pragma unroll
                for (int cc = 0; cc < 32; ++cc) {
                    const float4 v4 = *(const float4*)(vb + (size_t)cc * HW + q4 * 4);
                    o[cc] += v4.x * p4.x + v4.y * p4.y + v4.z * p4.z + v4.w * p4.w;
                }
            }
        }
    }

    // epilogue: normalize by l and store
    {
        const int i = threadIdx.x & 31;
        const int cg = threadIdx.x >> 5;
        const float inv = 1.f / ll[i];
        float* ab = ATT + ((size_t)b * (4 * CC) + g * CC + cg * 32) * HW + i0 + i;
        #pragma unroll
        for (int cc = 0; cc < 32; ++cc)
            ab[(size_t)cc * HW] = o[cc] * inv;
    }
}

// ---------------------------------------------------------------------------
// BatchNorm: per-channel stats then elementwise apply (in place on d_out)
// ---------------------------------------------------------------------------
__global__ void bnstats(const float* __restrict__ out, float* __restrict__ mean,
                        float* __restrict__ rstd) {
    const int c = blockIdx.x;
    float s = 0.f, s2 = 0.f;
    for (int e = threadIdx.x; e < BB * HW; e += 256) {
        int b = e / HW, i = e - b * HW;
        float v = out[((size_t)b * CC + c) * HW + i];
        s += v; s2 += v * v;
    }
    __shared__ float rs[256], rs2[256];
    rs[threadIdx.x] = s; rs2[threadIdx.x] = s2;
    __syncthreads();
    for (int st = 128; st > 0; st >>= 1) {
        if (threadIdx.x < st) {
            rs[threadIdx.x] += rs[threadIdx.x + st];
            rs2[threadIdx.x] += rs2[threadIdx.x + st];
        }
        __syncthreads();
    }
    if (threadIdx.x == 0) {
        const float n = (float)(BB * HW);
        float m = rs[0] / n;
        float var = rs2[0] / n - m * m;
        mean[c] = m;
        rstd[c] = rsqrtf(var + 1e-5f);
    }
}

__global__ void bnapply(float* __restrict__ out, const float* __restrict__ mean,
                        const float* __restrict__ rstd, const float* __restrict__ gamma,
                        const float* __restrict__ beta) {
    size_t idx = (size_t)blockIdx.x * 256 + threadIdx.x;
    if (idx < (size_t)BB * CC * HW) {
        int c = (int)((idx / HW) % CC);
        out[idx] = (out[idx] - mean[c]) * rstd[c] * gamma[c] + beta[c];
    }
}

// ---------------------------------------------------------------------------
extern "C" void kernel_launch(void* const* d_in, const int* in_sizes, int n_in,
                              void* d_out, int out_size, void* d_ws, size_t ws_size,
                              hipStream_t stream) {
    const float* x     = (const float*)d_in[0];
    const float* wq1   = (const float*)d_in[1];
    const float* wq3   = (const float*)d_in[2];
    const float* wq5   = (const float*)d_in[3];
    const float* wq7   = (const float*)d_in[4];
    const float* wk    = (const float*)d_in[5];
    const float* wv    = (const float*)d_in[6];
    const float* wproj = (const float*)d_in[7];
    const float* gamma = (const float*)d_in[8];
    const float* beta  = (const float*)d_in[9];
    float* out = (float*)d_out;

    float* ws   = (float*)d_ws;
    float* K    = ws;                         // B*32*HW     = 401408
    float* V    = K + (size_t)BB * RCH * HW;  // B*256*HW    = 3211264
    float* Qb   = V + (size_t)BB * CC * HW;   // 4*B*32*HW   = 1605632
    float* ATT  = Qb + (size_t)4 * BB * RCH * HW;  // B*1024*HW = 12845056
    float* mean = ATT + (size_t)BB * 4 * CC * HW;
    float* rstd = mean + CC;

    const size_t QSZ = (size_t)BB * RCH * HW;
    dim3 blk(256);

    // k, v, q1 (1x1 convs)
    gemm1x1<<<dim3(RCH / 16, HW / 64, BB), blk, 0, stream>>>(x, wk, nullptr, K, CC, RCH);
    gemm1x1<<<dim3(CC / 16, HW / 64, BB), blk, 0, stream>>>(x, wv, nullptr, V, CC, CC);
    gemm1x1<<<dim3(RCH / 16, HW / 64, BB), blk, 0, stream>>>(x, wq1, nullptr, Qb, CC, RCH);

    // q3/q5/q7 direct convs
    qconv<3><<<dim3((HW + 255) / 256, BB), blk, 0, stream>>>(x, wq3, Qb + 1 * QSZ);
    qconv<5><<<dim3((HW + 255) / 256, BB), blk, 0, stream>>>(x, wq5, Qb + 2 * QSZ);
    qconv<7><<<dim3((HW + 255) / 256, BB), blk, 0, stream>>>(x, wq7, Qb + 3 * QSZ);

    // flash attention: all 4 branches
    flashattn<<<dim3(HW / 32, BB, 4), blk, 0, stream>>>(Qb, K, V, ATT);

    // projection + residual -> d_out (pre-BN)
    gemm1x1<<<dim3(CC / 16, HW / 64, BB), blk, 0, stream>>>(ATT, wproj, x, out, 4 * CC, CC);

    // BatchNorm (training-mode batch stats)
    bnstats<<<dim3(CC), blk, 0, stream>>>(out, mean, rstd);
    bnapply<<<dim3((BB * CC * HW + 255) / 256), blk, 0, stream>>>(out, mean, rstd, gamma, beta);
}

// Round 2
// 25721.689 us; speedup vs baseline: 2.3396x; 2.3396x over previous
//
#include <hip/hip_runtime.h>
#include <math.h>

#define HW 3136
#define WIDTH 56
#define CC 256
#define BB 4
#define RCH 32

// ---------------------------------------------------------------------------
// Generic 1x1-conv GEMM: out[b,co,i] = sum_c w[co*Cin+c] * in[b,c,i] (+res)
// grid: (Cout/16, HW/64, B), block 256 = (16 i-lanes) x (16 co-lanes)
// ---------------------------------------------------------------------------
__global__ __launch_bounds__(256) void gemm1x1(
    const float* __restrict__ in, const float* __restrict__ w,
    const float* __restrict__ res, float* __restrict__ out,
    int Cin, int Cout) {
    const int tx = threadIdx.x & 15;   // i within tile (x4 unroll)
    const int ty = threadIdx.x >> 4;   // co within tile
    const int i0 = blockIdx.y * 64;
    const int co0 = blockIdx.x * 16;
    const int b = blockIdx.z;

    __shared__ float xs[32][64];
    __shared__ float wsl[16][33];

    float acc[4] = {0.f, 0.f, 0.f, 0.f};
    const float* inb = in + (size_t)b * Cin * HW;

    for (int c0 = 0; c0 < Cin; c0 += 32) {
        #pragma unroll
        for (int k = 0; k < 8; ++k) {
            int e = threadIdx.x + k * 256;
            int r = e >> 6, col = e & 63;
            xs[r][col] = inb[(size_t)(c0 + r) * HW + i0 + col];
        }
        #pragma unroll
        for (int k = 0; k < 2; ++k) {
            int e = threadIdx.x + k * 256;
            int r = e >> 5, col = e & 31;
            wsl[r][col] = w[(size_t)(co0 + r) * Cin + c0 + col];
        }
        __syncthreads();
        #pragma unroll
        for (int c = 0; c < 32; ++c) {
            float wv = wsl[ty][c];
            #pragma unroll
            for (int u = 0; u < 4; ++u)
                acc[u] += wv * xs[c][tx + 16 * u];
        }
        __syncthreads();
    }

    size_t obase = ((size_t)b * Cout + co0 + ty) * HW + i0 + tx;
    if (res) {
        #pragma unroll
        for (int u = 0; u < 4; ++u)
            out[obase + 16 * u] = acc[u] + res[obase + 16 * u];
    } else {
        #pragma unroll
        for (int u = 0; u < 4; ++u)
            out[obase + 16 * u] = acc[u];
    }
}

// ---------------------------------------------------------------------------
// Direct KxK conv producing q[b, r(32), hw]. grid: (ceil(HW/256), B), block 256
// Weights staged in LDS in [c'][tap][r] order (r-broadcast reads).
// ---------------------------------------------------------------------------
template <int KS>
__global__ __launch_bounds__(256) void qconv(
    const float* __restrict__ x, const float* __restrict__ w,
    float* __restrict__ q) {
    constexpr int P = (KS - 1) / 2;
    constexpr int KT = KS * KS;
    const int b = blockIdx.y;
    const int i = blockIdx.x * 256 + threadIdx.x;
    const int y = i / WIDTH, xc = i % WIDTH;
    const bool valid = (i < HW);

    __shared__ float wl[8][KT][32];

    float acc[32];
    #pragma unroll
    for (int r = 0; r < 32; ++r) acc[r] = 0.f;

    for (int c0 = 0; c0 < CC; c0 += 8) {
        for (int e = threadIdx.x; e < 8 * KT * 32; e += 256) {
            int r = e & 31;
            int ct = e >> 5;
            int t = ct % KT, cp = ct / KT;
            wl[cp][t][r] = w[((size_t)(r << 8) + c0 + cp) * KT + t];
        }
        __syncthreads();
        if (valid) {
            for (int cp = 0; cp < 8; ++cp) {
                const float* xr = x + ((size_t)b * CC + c0 + cp) * HW;
                for (int t = 0; t < KT; ++t) {
                    int dy = t / KS - P, dx = t % KS - P;
                    int yy = y + dy, xx = xc + dx;
                    float xv = (yy >= 0 && yy < WIDTH && xx >= 0 && xx < WIDTH)
                                   ? xr[yy * WIDTH + xx] : 0.f;
                    #pragma unroll
                    for (int r = 0; r < 32; ++r) acc[r] += wl[cp][t][r] * xv;
                }
            }
        }
        __syncthreads();
    }
    if (valid) {
        #pragma unroll
        for (int r = 0; r < 32; ++r)
            q[((size_t)b * RCH + r) * HW + i] = acc[r];
    }
}

// ---------------------------------------------------------------------------
// Flash attention over one branch g: att[b, c, i] = sum_j v[c,j] softmax_j(q_i.k_j*scale)
// grid: (HW/32, B, 4 branches), block 256 (4 waves).
// Wave w owns query rows w*8..w*8+7 for scores; PV threads: i=t%32, cgroup=t/32.
// ---------------------------------------------------------------------------
__global__ __launch_bounds__(256) void flashattn(
    const float* __restrict__ Q, const float* __restrict__ K,
    const float* __restrict__ V, float* __restrict__ ATT) {
    const int b = blockIdx.y, g = blockIdx.z;
    const int i0 = blockIdx.x * 32;
    const float scale = 0.17677669529663687f;  // 1/sqrt(32)

    __shared__ float ql[32][33];                  // [r][i]
    __shared__ float kl[32][64];                  // [r][j]
    // Row stride 68 floats: keeps 16B alignment for float4 reads and spreads
    // the 32 i-lanes over 8 banks (was 32-way conflict at stride 64).
    __shared__ __align__(16) float pl[32][68];    // [i][j(padded)]
    __shared__ float ml[32], ll[32], al[32];

    const int lane = threadIdx.x & 63;
    const int wv = threadIdx.x >> 6;

    const float* Qg = Q + ((size_t)(g * BB + b) * RCH) * HW;
    const float* Kb = K + (size_t)b * RCH * HW;

    // load q tile [32r][32i]
    #pragma unroll
    for (int k = 0; k < 4; ++k) {
        int e = threadIdx.x + k * 256;
        int r = e >> 5, ii = e & 31;
        ql[r][ii] = Qg[(size_t)r * HW + i0 + ii];
    }
    if (threadIdx.x < 32) { ml[threadIdx.x] = -1e30f; ll[threadIdx.x] = 0.f; }

    float o[32];
    #pragma unroll
    for (int cc = 0; cc < 32; ++cc) o[cc] = 0.f;

    __syncthreads();

    for (int jt = 0; jt < HW / 64; ++jt) {
        const int j0 = jt * 64;
        // K tile
        #pragma unroll
        for (int k = 0; k < 8; ++k) {
            int e = threadIdx.x + k * 256;
            int r = e >> 6, j = e & 63;
            kl[r][j] = Kb[(size_t)r * HW + j0 + j];
        }
        __syncthreads();  // k ready; prev-iter PV done (pl safe to overwrite)

        // scores + online softmax (wave-owned rows)
        #pragma unroll
        for (int ii = 0; ii < 8; ++ii) {
            const int i = wv * 8 + ii;
            float s = 0.f;
            #pragma unroll
            for (int r = 0; r < 32; ++r) s += ql[r][i] * kl[r][lane];
            s *= scale;
            float mx = s;
            #pragma unroll
            for (int off = 1; off < 64; off <<= 1) mx = fmaxf(mx, __shfl_xor(mx, off));
            float m_old = ml[i];
            float m_new = fmaxf(m_old, mx);
            float p = __expf(s - m_new);
            float sm = p;
            #pragma unroll
            for (int off = 1; off < 64; off <<= 1) sm += __shfl_xor(sm, off);
            pl[i][lane] = p;
            if (lane == 0) {
                float a = __expf(m_old - m_new);
                al[i] = a;
                ml[i] = m_new;
                ll[i] = ll[i] * a + sm;
            }
        }
        __syncthreads();  // p/alpha ready

        // PV: o[c,i] = o*alpha + sum_j v[c,j] * p[i,j]
        {
            const int i = threadIdx.x & 31;
            const int cg = threadIdx.x >> 5;
            const float a = al[i];
            #pragma unroll
            for (int cc = 0; cc < 32; ++cc) o[cc] *= a;
            const float* vb = V + ((size_t)b * CC + cg * 32) * HW + j0;
            const float4* pr = (const float4*)(&pl[i][0]);
            #pragma unroll
            for (int q4 = 0; q4 < 16; ++q4) {
                const float4 p4 = pr[q4];
                #pragma unroll
                for (int cc = 0; cc < 32; ++cc) {
                    const float4 v4 = *(const float4*)(vb + (size_t)cc * HW + q4 * 4);
                    o[cc] += v4.x * p4.x + v4.y * p4.y + v4.z * p4.z + v4.w * p4.w;
                }
            }
        }
    }

    // epilogue: normalize by l and store
    {
        const int i = threadIdx.x & 31;
        const int cg = threadIdx.x >> 5;
        const float inv = 1.f / ll[i];
        float* ab = ATT + ((size_t)b * (4 * CC) + g * CC + cg * 32) * HW + i0 + i;
        #pragma unroll
        for (int cc = 0; cc < 32; ++cc)
            ab[(size_t)cc * HW] = o[cc] * inv;
    }
}

// ---------------------------------------------------------------------------
// BatchNorm: per-channel stats then elementwise apply (in place on d_out)
// ---------------------------------------------------------------------------
__global__ __launch_bounds__(256) void bnstats(
    const float* __restrict__ out, float* __restrict__ mean,
    float* __restrict__ rstd) {
    const int c = blockIdx.x;
    float s = 0.f, s2 = 0.f;
    for (int e = threadIdx.x; e < BB * HW; e += 256) {
        int b = e / HW, i = e - b * HW;
        float v = out[((size_t)b * CC + c) * HW + i];
        s += v; s2 += v * v;
    }
    __shared__ float rs[256], rs2[256];
    rs[threadIdx.x] = s; rs2[threadIdx.x] = s2;
    __syncthreads();
    for (int st = 128; st > 0; st >>= 1) {
        if (threadIdx.x < st) {
            rs[threadIdx.x] += rs[threadIdx.x + st];
            rs2[threadIdx.x] += rs2[threadIdx.x + st];
        }
        __syncthreads();
    }
    if (threadIdx.x == 0) {
        const float n = (float)(BB * HW);
        float m = rs[0] / n;
        float var = rs2[0] / n - m * m;
        mean[c] = m;
        rstd[c] = rsqrtf(var + 1e-5f);
    }
}

__global__ __launch_bounds__(256) void bnapply(
    float* __restrict__ out, const float* __restrict__ mean,
    const float* __restrict__ rstd, const float* __restrict__ gamma,
    const float* __restrict__ beta) {
    size_t idx = (size_t)blockIdx.x * 256 + threadIdx.x;
    if (idx < (size_t)BB * CC * HW) {
        int c = (int)((idx / HW) % CC);
        out[idx] = (out[idx] - mean[c]) * rstd[c] * gamma[c] + beta[c];
    }
}

// ---------------------------------------------------------------------------
extern "C" void kernel_launch(void* const* d_in, const int* in_sizes, int n_in,
                              void* d_out, int out_size, void* d_ws, size_t ws_size,
                              hipStream_t stream) {
    const float* x     = (const float*)d_in[0];
    const float* wq1   = (const float*)d_in[1];
    const float* wq3   = (const float*)d_in[2];
    const float* wq5   = (const float*)d_in[3];
    const float* wq7   = (const float*)d_in[4];
    const float* wk    = (const float*)d_in[5];
    const float* wv    = (const float*)d_in[6];
    const float* wproj = (const float*)d_in[7];
    const float* gamma = (const float*)d_in[8];
    const float* beta  = (const float*)d_in[9];
    float* out = (float*)d_out;

    float* ws   = (float*)d_ws;
    float* K    = ws;                         // B*32*HW     = 401408
    float* V    = K + (size_t)BB * RCH * HW;  // B*256*HW    = 3211264
    float* Qb   = V + (size_t)BB * CC * HW;   // 4*B*32*HW   = 1605632
    float* ATT  = Qb + (size_t)4 * BB * RCH * HW;  // B*1024*HW = 12845056
    float* mean = ATT + (size_t)BB * 4 * CC * HW;
    float* rstd = mean + CC;

    const size_t QSZ = (size_t)BB * RCH * HW;
    dim3 blk(256);

    // k, v, q1 (1x1 convs)
    gemm1x1<<<dim3(RCH / 16, HW / 64, BB), blk, 0, stream>>>(x, wk, nullptr, K, CC, RCH);
    gemm1x1<<<dim3(CC / 16, HW / 64, BB), blk, 0, stream>>>(x, wv, nullptr, V, CC, CC);
    gemm1x1<<<dim3(RCH / 16, HW / 64, BB), blk, 0, stream>>>(x, wq1, nullptr, Qb, CC, RCH);

    // q3/q5/q7 direct convs
    qconv<3><<<dim3((HW + 255) / 256, BB), blk, 0, stream>>>(x, wq3, Qb + 1 * QSZ);
    qconv<5><<<dim3((HW + 255) / 256, BB), blk, 0, stream>>>(x, wq5, Qb + 2 * QSZ);
    qconv<7><<<dim3((HW + 255) / 256, BB), blk, 0, stream>>>(x, wq7, Qb + 3 * QSZ);

    // flash attention: all 4 branches
    flashattn<<<dim3(HW / 32, BB, 4), blk, 0, stream>>>(Qb, K, V, ATT);

    // projection + residual -> d_out (pre-BN)
    gemm1x1<<<dim3(CC / 16, HW / 64, BB), blk, 0, stream>>>(ATT, wproj, x, out, 4 * CC, CC);

    // BatchNorm (training-mode batch stats)
    bnstats<<<dim3(CC), blk, 0, stream>>>(out, mean, rstd);
    bnapply<<<dim3((BB * CC * HW + 255) / 256), blk, 0, stream>>>(out, mean, rstd, gamma, beta);
}

// Round 3
// 4953.414 us; speedup vs baseline: 12.1487x; 5.1927x over previous
//
#include <hip/hip_runtime.h>
#include <hip/hip_bf16.h>
#include <math.h>

#define HW 3136
#define WIDTH 56
#define CC 256
#define BB 4
#define RCH 32

using bf16x8 = __attribute__((ext_vector_type(8))) short;
using f32x4  = __attribute__((ext_vector_type(4))) float;

static __device__ __forceinline__ unsigned short f2bf(float f) {
    __hip_bfloat16 h = __float2bfloat16(f);
    return *reinterpret_cast<unsigned short*>(&h);
}

// ---------------------------------------------------------------------------
// 1x1 conv GEMM, fp32 out (+optional residual). Used for wproj.
// grid: (Cout/16, HW/64, B), block 256
// ---------------------------------------------------------------------------
__global__ __launch_bounds__(256) void gemm1x1(
    const float* __restrict__ in, const float* __restrict__ w,
    const float* __restrict__ res, float* __restrict__ out,
    int Cin, int Cout) {
    const int tx = threadIdx.x & 15;
    const int ty = threadIdx.x >> 4;
    const int i0 = blockIdx.y * 64;
    const int co0 = blockIdx.x * 16;
    const int b = blockIdx.z;

    __shared__ float xs[32][64];
    __shared__ float wsl[16][33];

    float acc[4] = {0.f, 0.f, 0.f, 0.f};
    const float* inb = in + (size_t)b * Cin * HW;

    for (int c0 = 0; c0 < Cin; c0 += 32) {
        #pragma unroll
        for (int k = 0; k < 8; ++k) {
            int e = threadIdx.x + k * 256;
            int r = e >> 6, col = e & 63;
            xs[r][col] = inb[(size_t)(c0 + r) * HW + i0 + col];
        }
        #pragma unroll
        for (int k = 0; k < 2; ++k) {
            int e = threadIdx.x + k * 256;
            int r = e >> 5, col = e & 31;
            wsl[r][col] = w[(size_t)(co0 + r) * Cin + c0 + col];
        }
        __syncthreads();
        #pragma unroll
        for (int c = 0; c < 32; ++c) {
            float wv = wsl[ty][c];
            #pragma unroll
            for (int u = 0; u < 4; ++u)
                acc[u] += wv * xs[c][tx + 16 * u];
        }
        __syncthreads();
    }

    size_t obase = ((size_t)b * Cout + co0 + ty) * HW + i0 + tx;
    if (res) {
        #pragma unroll
        for (int u = 0; u < 4; ++u)
            out[obase + 16 * u] = acc[u] + res[obase + 16 * u];
    } else {
        #pragma unroll
        for (int u = 0; u < 4; ++u)
            out[obase + 16 * u] = acc[u];
    }
}

// ---------------------------------------------------------------------------
// 1x1 conv GEMM, bf16 out [b][co][hw]. Used for V.
// ---------------------------------------------------------------------------
__global__ __launch_bounds__(256) void gemm1x1_v(
    const float* __restrict__ in, const float* __restrict__ w,
    unsigned short* __restrict__ out, int Cin, int Cout) {
    const int tx = threadIdx.x & 15;
    const int ty = threadIdx.x >> 4;
    const int i0 = blockIdx.y * 64;
    const int co0 = blockIdx.x * 16;
    const int b = blockIdx.z;

    __shared__ float xs[32][64];
    __shared__ float wsl[16][33];

    float acc[4] = {0.f, 0.f, 0.f, 0.f};
    const float* inb = in + (size_t)b * Cin * HW;

    for (int c0 = 0; c0 < Cin; c0 += 32) {
        #pragma unroll
        for (int k = 0; k < 8; ++k) {
            int e = threadIdx.x + k * 256;
            int r = e >> 6, col = e & 63;
            xs[r][col] = inb[(size_t)(c0 + r) * HW + i0 + col];
        }
        #pragma unroll
        for (int k = 0; k < 2; ++k) {
            int e = threadIdx.x + k * 256;
            int r = e >> 5, col = e & 31;
            wsl[r][col] = w[(size_t)(co0 + r) * Cin + c0 + col];
        }
        __syncthreads();
        #pragma unroll
        for (int c = 0; c < 32; ++c) {
            float wv = wsl[ty][c];
            #pragma unroll
            for (int u = 0; u < 4; ++u)
                acc[u] += wv * xs[c][tx + 16 * u];
        }
        __syncthreads();
    }

    size_t obase = ((size_t)b * Cout + co0 + ty) * HW + i0 + tx;
    #pragma unroll
    for (int u = 0; u < 4; ++u)
        out[obase + 16 * u] = f2bf(acc[u]);
}

// ---------------------------------------------------------------------------
// 1x1 conv, Cout=32, TRANSPOSED bf16 out: outt[b][hw][32]. Used for K and Q1.
// grid: (HW/64, B), block 256. Thread: i = t&63, co-octet = t>>6.
// ---------------------------------------------------------------------------
__global__ __launch_bounds__(256) void gemm_qk32(
    const float* __restrict__ in, const float* __restrict__ w,
    unsigned short* __restrict__ outt) {
    const int i = threadIdx.x & 63;
    const int cog = threadIdx.x >> 6;
    const int i0 = blockIdx.x * 64;
    const int b = blockIdx.y;

    __shared__ float xs[32][64];
    __shared__ float wsl[32][33];

    float acc[8] = {0.f,0.f,0.f,0.f,0.f,0.f,0.f,0.f};
    const float* inb = in + (size_t)b * CC * HW;

    for (int c0 = 0; c0 < CC; c0 += 32) {
        #pragma unroll
        for (int k = 0; k < 8; ++k) {
            int e = threadIdx.x + k * 256;
            int r = e >> 6, col = e & 63;
            xs[r][col] = inb[(size_t)(c0 + r) * HW + i0 + col];
        }
        #pragma unroll
        for (int k = 0; k < 4; ++k) {
            int e = threadIdx.x + k * 256;
            int r = e >> 5, col = e & 31;
            wsl[r][col] = w[(size_t)r * CC + c0 + col];
        }
        __syncthreads();
        #pragma unroll
        for (int c = 0; c < 32; ++c) {
            float xv = xs[c][i];
            #pragma unroll
            for (int u = 0; u < 8; ++u)
                acc[u] += wsl[cog * 8 + u][c] * xv;
        }
        __syncthreads();
    }
    unsigned int pk[4];
    #pragma unroll
    for (int u = 0; u < 4; ++u)
        pk[u] = (unsigned int)f2bf(acc[2 * u]) | ((unsigned int)f2bf(acc[2 * u + 1]) << 16);
    *(uint4*)(outt + ((size_t)b * HW + i0 + i) * 32 + cog * 8) = *(uint4*)pk;
}

// ---------------------------------------------------------------------------
// Direct KxK conv producing TRANSPOSED bf16 q[b][hw][32].
// grid: (ceil(HW/256), B), block 256
// ---------------------------------------------------------------------------
template <int KS>
__global__ __launch_bounds__(256) void qconv(
    const float* __restrict__ x, const float* __restrict__ w,
    unsigned short* __restrict__ q) {
    constexpr int P = (KS - 1) / 2;
    constexpr int KT = KS * KS;
    const int b = blockIdx.y;
    const int i = blockIdx.x * 256 + threadIdx.x;
    const int y = i / WIDTH, xc = i % WIDTH;
    const bool valid = (i < HW);

    __shared__ float wl[8][KT][32];

    float acc[32];
    #pragma unroll
    for (int r = 0; r < 32; ++r) acc[r] = 0.f;

    for (int c0 = 0; c0 < CC; c0 += 8) {
        for (int e = threadIdx.x; e < 8 * KT * 32; e += 256) {
            int r = e & 31;
            int ct = e >> 5;
            int t = ct % KT, cp = ct / KT;
            wl[cp][t][r] = w[((size_t)(r << 8) + c0 + cp) * KT + t];
        }
        __syncthreads();
        if (valid) {
            for (int cp = 0; cp < 8; ++cp) {
                const float* xr = x + ((size_t)b * CC + c0 + cp) * HW;
                for (int t = 0; t < KT; ++t) {
                    int dy = t / KS - P, dx = t % KS - P;
                    int yy = y + dy, xx = xc + dx;
                    float xv = (yy >= 0 && yy < WIDTH && xx >= 0 && xx < WIDTH)
                                   ? xr[yy * WIDTH + xx] : 0.f;
                    #pragma unroll
                    for (int r = 0; r < 32; ++r) acc[r] += wl[cp][t][r] * xv;
                }
            }
        }
        __syncthreads();
    }
    if (valid) {
        unsigned short* dst = q + ((size_t)b * HW + i) * 32;
        unsigned int pk[16];
        #pragma unroll
        for (int u = 0; u < 16; ++u)
            pk[u] = (unsigned int)f2bf(acc[2 * u]) | ((unsigned int)f2bf(acc[2 * u + 1]) << 16);
        #pragma unroll
        for (int u = 0; u < 4; ++u)
            *(uint4*)(dst + u * 8) = *(uint4*)(pk + u * 4);
    }
}

// ---------------------------------------------------------------------------
// MFMA flash attention.
// grid: (HW/64, B, 4 branches), block 256 (4 waves).
// Per block: 64 query rows. Per 64-j tile: stage Kt(64x32) + V(256x64) in LDS.
// QK phase: wave w owns i-strip w*16..+15 (4 MFMAs) + in-register online
// softmax (16-lane butterflies), P->LDS bf16. PV phase: wave w owns channels
// w*64..+63 (32 MFMAs, every V element read once from LDS).
// LDS rows padded to 80B/144B (16B-multiples) -> <=2-way bank aliasing.
// ---------------------------------------------------------------------------
__global__ __launch_bounds__(256) void flashmfma(
    const unsigned short* __restrict__ Qt, const unsigned short* __restrict__ Kt,
    const unsigned short* __restrict__ Vb, float* __restrict__ ATT) {
    const int b = blockIdx.y, g = blockIdx.z;
    const int i0 = blockIdx.x * 64;
    const int t = threadIdx.x;
    const int lane = t & 63;
    const int w = t >> 6;
    const int lg = lane >> 4;
    const int li = lane & 15;

    __shared__ unsigned short Qs[64][40];   // [i][r], 80B rows
    __shared__ unsigned short Ks[64][40];   // [j][r]
    __shared__ unsigned short Vs[256][72];  // [c][j], 144B rows
    __shared__ unsigned short Ps[64][72];   // [i][j]
    __shared__ float als[64];
    __shared__ float lls[64];

    // stage Q once (rows i0..i0+63)
    {
        int ir = t >> 2, sl = t & 3;
        *(uint4*)(&Qs[ir][sl * 8]) =
            *(const uint4*)(Qt + ((size_t)(g * BB + b) * HW + i0 + ir) * 32 + sl * 8);
    }

    f32x4 acc[4][4];
    #pragma unroll
    for (int ct = 0; ct < 4; ++ct)
        #pragma unroll
        for (int is = 0; is < 4; ++is)
            acc[ct][is] = (f32x4){0.f, 0.f, 0.f, 0.f};

    float m_run[4], l_run[4];
    #pragma unroll
    for (int r = 0; r < 4; ++r) { m_run[r] = -1e30f; l_run[r] = 0.f; }

    const float sc = 0.17677669529663687f * 1.4426950408889634f;  // scale*log2(e)

    for (int jt = 0; jt < HW / 64; ++jt) {
        const int j0 = jt * 64;
        __syncthreads();  // prev-iter LDS reads done
        {
            int jr = t >> 2, sl = t & 3;
            *(uint4*)(&Ks[jr][sl * 8]) =
                *(const uint4*)(Kt + ((size_t)b * HW + j0 + jr) * 32 + sl * 8);
        }
        {
            int vr = t >> 3, sl = t & 7;
            const unsigned short* vsrc = Vb + ((size_t)b * CC + vr) * HW + j0 + sl * 8;
            #pragma unroll
            for (int p = 0; p < 8; ++p)
                *(uint4*)(&Vs[vr + p * 32][sl * 8]) =
                    *(const uint4*)(vsrc + (size_t)p * 32 * HW);
        }
        __syncthreads();

        // ---- QK^T: S[i=lg*4+r][j=j2*16+li] for my strip
        bf16x8 aq = *(const bf16x8*)(&Qs[w * 16 + li][lg * 8]);
        f32x4 S[4];
        #pragma unroll
        for (int j2 = 0; j2 < 4; ++j2) {
            bf16x8 bk = *(const bf16x8*)(&Ks[j2 * 16 + li][lg * 8]);
            S[j2] = __builtin_amdgcn_mfma_f32_16x16x32_bf16(
                aq, bk, (f32x4){0.f, 0.f, 0.f, 0.f}, 0, 0, 0);
        }

        // ---- online softmax (rows lg*4+r, j distributed over li-lanes)
        float prow[4][4];
        #pragma unroll
        for (int r = 0; r < 4; ++r) {
            float t0 = S[0][r] * sc, t1 = S[1][r] * sc;
            float t2 = S[2][r] * sc, t3 = S[3][r] * sc;
            float mx = fmaxf(fmaxf(t0, t1), fmaxf(t2, t3));
            #pragma unroll
            for (int off = 1; off < 16; off <<= 1) mx = fmaxf(mx, __shfl_xor(mx, off));
            float mnew = fmaxf(m_run[r], mx);
            float al = exp2f(m_run[r] - mnew);
            float p0 = exp2f(t0 - mnew), p1 = exp2f(t1 - mnew);
            float p2 = exp2f(t2 - mnew), p3 = exp2f(t3 - mnew);
            float rs = p0 + p1 + p2 + p3;
            #pragma unroll
            for (int off = 1; off < 16; off <<= 1) rs += __shfl_xor(rs, off);
            l_run[r] = l_run[r] * al + rs;
            m_run[r] = mnew;
            prow[r][0] = p0; prow[r][1] = p1; prow[r][2] = p2; prow[r][3] = p3;
            if (li == 0) als[w * 16 + lg * 4 + r] = al;
        }
        #pragma unroll
        for (int r = 0; r < 4; ++r)
            #pragma unroll
            for (int j2 = 0; j2 < 4; ++j2)
                Ps[w * 16 + lg * 4 + r][j2 * 16 + li] = f2bf(prow[r][j2]);

        __syncthreads();  // P/alpha visible to all waves

        // ---- PV: wave owns channels w*64..+63
        bf16x8 bp[4][2];
        #pragma unroll
        for (int is = 0; is < 4; ++is)
            #pragma unroll
            for (int ks = 0; ks < 2; ++ks)
                bp[is][ks] = *(const bf16x8*)(&Ps[is * 16 + li][ks * 32 + lg * 8]);

        float ar[4];
        #pragma unroll
        for (int is = 0; is < 4; ++is) ar[is] = als[is * 16 + li];

        #pragma unroll
        for (int ct = 0; ct < 4; ++ct) {
            #pragma unroll
            for (int is = 0; is < 4; ++is) {
                #pragma unroll
                for (int r = 0; r < 4; ++r) acc[ct][is][r] *= ar[is];
            }
            #pragma unroll
            for (int ks = 0; ks < 2; ++ks) {
                bf16x8 av = *(const bf16x8*)(&Vs[w * 64 + ct * 16 + li][ks * 32 + lg * 8]);
                #pragma unroll
                for (int is = 0; is < 4; ++is)
                    acc[ct][is] = __builtin_amdgcn_mfma_f32_16x16x32_bf16(
                        av, bp[is][ks], acc[ct][is], 0, 0, 0);
            }
        }
    }

    if (li == 0) {
        #pragma unroll
        for (int r = 0; r < 4; ++r) lls[w * 16 + lg * 4 + r] = l_run[r];
    }
    __syncthreads();

    float invl[4];
    #pragma unroll
    for (int is = 0; is < 4; ++is) invl[is] = 1.f / lls[is * 16 + li];

    #pragma unroll
    for (int ct = 0; ct < 4; ++ct) {
        #pragma unroll
        for (int is = 0; is < 4; ++is) {
            #pragma unroll
            for (int r = 0; r < 4; ++r) {
                int c = w * 64 + ct * 16 + lg * 4 + r;
                ATT[((size_t)b * (4 * CC) + g * CC + c) * HW + i0 + is * 16 + li] =
                    acc[ct][is][r] * invl[is];
            }
        }
    }
}

// ---------------------------------------------------------------------------
// BatchNorm
// ---------------------------------------------------------------------------
__global__ __launch_bounds__(256) void bnstats(
    const float* __restrict__ out, float* __restrict__ mean,
    float* __restrict__ rstd) {
    const int c = blockIdx.x;
    float s = 0.f, s2 = 0.f;
    for (int e = threadIdx.x; e < BB * HW; e += 256) {
        int b = e / HW, i = e - b * HW;
        float v = out[((size_t)b * CC + c) * HW + i];
        s += v; s2 += v * v;
    }
    __shared__ float rs[256], rs2[256];
    rs[threadIdx.x] = s; rs2[threadIdx.x] = s2;
    __syncthreads();
    for (int st = 128; st > 0; st >>= 1) {
        if (threadIdx.x < st) {
            rs[threadIdx.x] += rs[threadIdx.x + st];
            rs2[threadIdx.x] += rs2[threadIdx.x + st];
        }
        __syncthreads();
    }
    if (threadIdx.x == 0) {
        const float n = (float)(BB * HW);
        float m = rs[0] / n;
        float var = rs2[0] / n - m * m;
        mean[c] = m;
        rstd[c] = rsqrtf(var + 1e-5f);
    }
}

__global__ __launch_bounds__(256) void bnapply(
    float* __restrict__ out, const float* __restrict__ mean,
    const float* __restrict__ rstd, const float* __restrict__ gamma,
    const float* __restrict__ beta) {
    size_t idx = (size_t)blockIdx.x * 256 + threadIdx.x;
    if (idx < (size_t)BB * CC * HW) {
        int c = (int)((idx / HW) % CC);
        out[idx] = (out[idx] - mean[c]) * rstd[c] * gamma[c] + beta[c];
    }
}

// ---------------------------------------------------------------------------
extern "C" void kernel_launch(void* const* d_in, const int* in_sizes, int n_in,
                              void* d_out, int out_size, void* d_ws, size_t ws_size,
                              hipStream_t stream) {
    const float* x     = (const float*)d_in[0];
    const float* wq1   = (const float*)d_in[1];
    const float* wq3   = (const float*)d_in[2];
    const float* wq5   = (const float*)d_in[3];
    const float* wq7   = (const float*)d_in[4];
    const float* wk    = (const float*)d_in[5];
    const float* wv    = (const float*)d_in[6];
    const float* wproj = (const float*)d_in[7];
    const float* gamma = (const float*)d_in[8];
    const float* beta  = (const float*)d_in[9];
    float* out = (float*)d_out;

    float* ATT  = (float*)d_ws;                      // B*4C*HW fp32
    float* mean = ATT + (size_t)BB * 4 * CC * HW;
    float* rstd = mean + CC;
    unsigned short* Kt = (unsigned short*)(rstd + CC);       // [B][HW][32] bf16
    unsigned short* Qt = Kt + (size_t)BB * HW * 32;          // [4g*B][HW][32] bf16
    unsigned short* Vb = Qt + (size_t)4 * BB * HW * 32;      // [B][C][HW] bf16

    const size_t QSLICE = (size_t)BB * HW * 32;
    dim3 blk(256);

    // K, Q1 (transposed bf16), V (bf16)
    gemm_qk32<<<dim3(HW / 64, BB), blk, 0, stream>>>(x, wk, Kt);
    gemm_qk32<<<dim3(HW / 64, BB), blk, 0, stream>>>(x, wq1, Qt);
    gemm1x1_v<<<dim3(CC / 16, HW / 64, BB), blk, 0, stream>>>(x, wv, Vb, CC, CC);

    // q3/q5/q7 direct convs (transposed bf16 out)
    qconv<3><<<dim3((HW + 255) / 256, BB), blk, 0, stream>>>(x, wq3, Qt + 1 * QSLICE);
    qconv<5><<<dim3((HW + 255) / 256, BB), blk, 0, stream>>>(x, wq5, Qt + 2 * QSLICE);
    qconv<7><<<dim3((HW + 255) / 256, BB), blk, 0, stream>>>(x, wq7, Qt + 3 * QSLICE);

    // MFMA flash attention, all 4 branches
    flashmfma<<<dim3(HW / 64, BB, 4), blk, 0, stream>>>(Qt, Kt, Vb, ATT);

    // projection + residual -> d_out (pre-BN)
    gemm1x1<<<dim3(CC / 16, HW / 64, BB), blk, 0, stream>>>(ATT, wproj, x, out, 4 * CC, CC);

    // BatchNorm
    bnstats<<<dim3(CC), blk, 0, stream>>>(out, mean, rstd);
    bnapply<<<dim3((BB * CC * HW + 255) / 256), blk, 0, stream>>>(out, mean, rstd, gamma, beta);
}

// Round 4
// 946.997 us; speedup vs baseline: 63.5458x; 5.2307x over previous
//
#include <hip/hip_runtime.h>
#include <hip/hip_bf16.h>
#include <math.h>

#define HW 3136
#define WIDTH 56
#define CC 256
#define BB 4
#define RCH 32

using bf16x8 = __attribute__((ext_vector_type(8))) short;
using f32x4  = __attribute__((ext_vector_type(4))) float;

static __device__ __forceinline__ unsigned short f2bf(float f) {
    __hip_bfloat16 h = __float2bfloat16(f);
    return *reinterpret_cast<unsigned short*>(&h);
}

// ---------------------------------------------------------------------------
// 1x1 conv GEMM, fp32 out (+optional residual). Used for wproj.
// ---------------------------------------------------------------------------
__global__ __launch_bounds__(256) void gemm1x1(
    const float* __restrict__ in, const float* __restrict__ w,
    const float* __restrict__ res, float* __restrict__ out,
    int Cin, int Cout) {
    const int tx = threadIdx.x & 15;
    const int ty = threadIdx.x >> 4;
    const int i0 = blockIdx.y * 64;
    const int co0 = blockIdx.x * 16;
    const int b = blockIdx.z;

    __shared__ float xs[32][64];
    __shared__ float wsl[16][33];

    float acc[4] = {0.f, 0.f, 0.f, 0.f};
    const float* inb = in + (size_t)b * Cin * HW;

    for (int c0 = 0; c0 < Cin; c0 += 32) {
        #pragma unroll
        for (int k = 0; k < 8; ++k) {
            int e = threadIdx.x + k * 256;
            int r = e >> 6, col = e & 63;
            xs[r][col] = inb[(size_t)(c0 + r) * HW + i0 + col];
        }
        #pragma unroll
        for (int k = 0; k < 2; ++k) {
            int e = threadIdx.x + k * 256;
            int r = e >> 5, col = e & 31;
            wsl[r][col] = w[(size_t)(co0 + r) * Cin + c0 + col];
        }
        __syncthreads();
        #pragma unroll
        for (int c = 0; c < 32; ++c) {
            float wv = wsl[ty][c];
            #pragma unroll
            for (int u = 0; u < 4; ++u)
                acc[u] += wv * xs[c][tx + 16 * u];
        }
        __syncthreads();
    }

    size_t obase = ((size_t)b * Cout + co0 + ty) * HW + i0 + tx;
    if (res) {
        #pragma unroll
        for (int u = 0; u < 4; ++u)
            out[obase + 16 * u] = acc[u] + res[obase + 16 * u];
    } else {
        #pragma unroll
        for (int u = 0; u < 4; ++u)
            out[obase + 16 * u] = acc[u];
    }
}

// ---------------------------------------------------------------------------
// 1x1 conv GEMM, bf16 out [b][co][hw]. Used for V.
// ---------------------------------------------------------------------------
__global__ __launch_bounds__(256) void gemm1x1_v(
    const float* __restrict__ in, const float* __restrict__ w,
    unsigned short* __restrict__ out, int Cin, int Cout) {
    const int tx = threadIdx.x & 15;
    const int ty = threadIdx.x >> 4;
    const int i0 = blockIdx.y * 64;
    const int co0 = blockIdx.x * 16;
    const int b = blockIdx.z;

    __shared__ float xs[32][64];
    __shared__ float wsl[16][33];

    float acc[4] = {0.f, 0.f, 0.f, 0.f};
    const float* inb = in + (size_t)b * Cin * HW;

    for (int c0 = 0; c0 < Cin; c0 += 32) {
        #pragma unroll
        for (int k = 0; k < 8; ++k) {
            int e = threadIdx.x + k * 256;
            int r = e >> 6, col = e & 63;
            xs[r][col] = inb[(size_t)(c0 + r) * HW + i0 + col];
        }
        #pragma unroll
        for (int k = 0; k < 2; ++k) {
            int e = threadIdx.x + k * 256;
            int r = e >> 5, col = e & 31;
            wsl[r][col] = w[(size_t)(co0 + r) * Cin + c0 + col];
        }
        __syncthreads();
        #pragma unroll
        for (int c = 0; c < 32; ++c) {
            float wv = wsl[ty][c];
            #pragma unroll
            for (int u = 0; u < 4; ++u)
                acc[u] += wv * xs[c][tx + 16 * u];
        }
        __syncthreads();
    }

    size_t obase = ((size_t)b * Cout + co0 + ty) * HW + i0 + tx;
    #pragma unroll
    for (int u = 0; u < 4; ++u)
        out[obase + 16 * u] = f2bf(acc[u]);
}

// ---------------------------------------------------------------------------
// 1x1 conv, Cout=32, TRANSPOSED bf16 out: outt[b][hw][32]. Used for K and Q1.
// ---------------------------------------------------------------------------
__global__ __launch_bounds__(256) void gemm_qk32(
    const float* __restrict__ in, const float* __restrict__ w,
    unsigned short* __restrict__ outt) {
    const int i = threadIdx.x & 63;
    const int cog = threadIdx.x >> 6;
    const int i0 = blockIdx.x * 64;
    const int b = blockIdx.y;

    __shared__ float xs[32][64];
    __shared__ float wsl[32][33];

    float acc[8] = {0.f,0.f,0.f,0.f,0.f,0.f,0.f,0.f};
    const float* inb = in + (size_t)b * CC * HW;

    for (int c0 = 0; c0 < CC; c0 += 32) {
        #pragma unroll
        for (int k = 0; k < 8; ++k) {
            int e = threadIdx.x + k * 256;
            int r = e >> 6, col = e & 63;
            xs[r][col] = inb[(size_t)(c0 + r) * HW + i0 + col];
        }
        #pragma unroll
        for (int k = 0; k < 4; ++k) {
            int e = threadIdx.x + k * 256;
            int r = e >> 5, col = e & 31;
            wsl[r][col] = w[(size_t)r * CC + c0 + col];
        }
        __syncthreads();
        #pragma unroll
        for (int c = 0; c < 32; ++c) {
            float xv = xs[c][i];
            #pragma unroll
            for (int u = 0; u < 8; ++u)
                acc[u] += wsl[cog * 8 + u][c] * xv;
        }
        __syncthreads();
    }
    unsigned int pk[4];
    #pragma unroll
    for (int u = 0; u < 4; ++u)
        pk[u] = (unsigned int)f2bf(acc[2 * u]) | ((unsigned int)f2bf(acc[2 * u + 1]) << 16);
    *(uint4*)(outt + ((size_t)b * HW + i0 + i) * 32 + cog * 8) = *(uint4*)pk;
}

// ---------------------------------------------------------------------------
// x transpose + bf16: xT[b][hw][c]. grid (HW/32, C/32, B), block 256 (32x8).
// ---------------------------------------------------------------------------
__global__ __launch_bounds__(256) void transpose_x(
    const float* __restrict__ x, unsigned short* __restrict__ xT) {
    __shared__ unsigned short tile[32][33];
    const int b = blockIdx.z;
    const int i0 = blockIdx.x * 32, c0 = blockIdx.y * 32;
    const int tx = threadIdx.x & 31, ty = threadIdx.x >> 5;
    #pragma unroll
    for (int k = 0; k < 4; ++k)
        tile[ty + k * 8][tx] = f2bf(x[((size_t)b * CC + c0 + ty + k * 8) * HW + i0 + tx]);
    __syncthreads();
    #pragma unroll
    for (int k = 0; k < 4; ++k)
        xT[((size_t)b * HW + i0 + ty + k * 8) * 256 + c0 + tx] = tile[tx][ty + k * 8];
}

// ---------------------------------------------------------------------------
// Weight repack: Wb[t][r][c] bf16 from w[r][c][t] fp32.
// ---------------------------------------------------------------------------
__global__ __launch_bounds__(256) void wprep(
    const float* __restrict__ w, unsigned short* __restrict__ Wb, int KT) {
    int e = blockIdx.x * 256 + threadIdx.x;
    if (e < KT * 32 * 256) {
        int c = e & 255, r = (e >> 8) & 31, t = e >> 13;
        Wb[e] = f2bf(w[((size_t)r * 256 + c) * KT + t]);
    }
}

// ---------------------------------------------------------------------------
// MFMA im2col q-conv: q[b][hw][32] = conv_KS(x) transposed bf16.
// grid (HW/64, B), block 256 (4 waves). Per block: 64 pixels x 32 r.
// A (x-patch) staged in LDS per 32-c chunk; B (weights) streamed from global
// (L1/L2-hot, same for all blocks). Column-OOB taps zeroed per-lane; row-OOB
// handled by zero-staging. 2 MFMAs per wave per (tap, c-chunk).
// ---------------------------------------------------------------------------
template <int KS>
__global__ __launch_bounds__(256) void qconv_mfma(
    const unsigned short* __restrict__ xT,  // [b][hw][256] bf16
    const unsigned short* __restrict__ Wb,  // [KT][32][256] bf16
    unsigned short* __restrict__ q) {       // [b][hw][32] bf16
    constexpr int P = (KS - 1) / 2;
    constexpr int KT = KS * KS;
    constexpr int ROWS = 64 + 114 * P;  // staged linear positions
    const int b = blockIdx.y;
    const int i0 = blockIdx.x * 64;
    const int t = threadIdx.x;
    const int lane = t & 63;
    const int w = t >> 6;
    const int li = lane & 15;
    const int lg = lane >> 4;

    __shared__ unsigned short xs[ROWS][40];  // rows padded to 80B -> 2-way max

    const int base = i0 - P * 57;            // linear idx of xs row 0
    const int mycol = (i0 + w * 16 + li) % WIDTH;

    f32x4 acc[2];
    acc[0] = (f32x4){0.f, 0.f, 0.f, 0.f};
    acc[1] = (f32x4){0.f, 0.f, 0.f, 0.f};

    const unsigned short* xTb = xT + (size_t)b * HW * 256;

    for (int c0 = 0; c0 < 256; c0 += 32) {
        __syncthreads();  // previous chunk's reads complete
        for (int e = t; e < ROWS * 4; e += 256) {
            int row = e >> 2, cs = e & 3;
            int gidx = base + row;
            uint4 val = make_uint4(0, 0, 0, 0);
            if (gidx >= 0 && gidx < HW)
                val = *(const uint4*)(xTb + (size_t)gidx * 256 + c0 + cs * 8);
            *(uint4*)(&xs[row][cs * 8]) = val;
        }
        __syncthreads();

        #pragma unroll
        for (int tap = 0; tap < KT; ++tap) {
            const int dx = tap % KS - P;
            const int poff = (tap / KS) * WIDTH + tap % KS;  // (dy+P)*56+(dx+P)
            bf16x8 a = *(const bf16x8*)(&xs[w * 16 + li + poff][lg * 8]);
            if ((unsigned)(mycol + dx) >= (unsigned)WIDTH)
                a = (bf16x8){0, 0, 0, 0, 0, 0, 0, 0};
            const unsigned short* wrow =
                Wb + (size_t)tap * 32 * 256 + c0 + lg * 8;
            bf16x8 b0 = *(const bf16x8*)(wrow + (size_t)li * 256);
            bf16x8 b1 = *(const bf16x8*)(wrow + (size_t)(16 + li) * 256);
            acc[0] = __builtin_amdgcn_mfma_f32_16x16x32_bf16(a, b0, acc[0], 0, 0, 0);
            acc[1] = __builtin_amdgcn_mfma_f32_16x16x32_bf16(a, b1, acc[1], 0, 0, 0);
        }
    }

    // D[m = pix: lg*4+reg][n = r: rs*16+li]
    unsigned short* qb = q + ((size_t)b * HW + i0 + w * 16 + lg * 4) * 32;
    #pragma unroll
    for (int rs = 0; rs < 2; ++rs)
        #pragma unroll
        for (int r = 0; r < 4; ++r)
            qb[(size_t)r * 32 + rs * 16 + li] = f2bf(acc[rs][r]);
}

// ---------------------------------------------------------------------------
// MFMA flash attention (unchanged from round 3).
// ---------------------------------------------------------------------------
__global__ __launch_bounds__(256) void flashmfma(
    const unsigned short* __restrict__ Qt, const unsigned short* __restrict__ Kt,
    const unsigned short* __restrict__ Vb, float* __restrict__ ATT) {
    const int b = blockIdx.y, g = blockIdx.z;
    const int i0 = blockIdx.x * 64;
    const int t = threadIdx.x;
    const int lane = t & 63;
    const int w = t >> 6;
    const int lg = lane >> 4;
    const int li = lane & 15;

    __shared__ unsigned short Qs[64][40];
    __shared__ unsigned short Ks[64][40];
    __shared__ unsigned short Vs[256][72];
    __shared__ unsigned short Ps[64][72];
    __shared__ float als[64];
    __shared__ float lls[64];

    {
        int ir = t >> 2, sl = t & 3;
        *(uint4*)(&Qs[ir][sl * 8]) =
            *(const uint4*)(Qt + ((size_t)(g * BB + b) * HW + i0 + ir) * 32 + sl * 8);
    }

    f32x4 acc[4][4];
    #pragma unroll
    for (int ct = 0; ct < 4; ++ct)
        #pragma unroll
        for (int is = 0; is < 4; ++is)
            acc[ct][is] = (f32x4){0.f, 0.f, 0.f, 0.f};

    float m_run[4], l_run[4];
    #pragma unroll
    for (int r = 0; r < 4; ++r) { m_run[r] = -1e30f; l_run[r] = 0.f; }

    const float sc = 0.17677669529663687f * 1.4426950408889634f;

    for (int jt = 0; jt < HW / 64; ++jt) {
        const int j0 = jt * 64;
        __syncthreads();
        {
            int jr = t >> 2, sl = t & 3;
            *(uint4*)(&Ks[jr][sl * 8]) =
                *(const uint4*)(Kt + ((size_t)b * HW + j0 + jr) * 32 + sl * 8);
        }
        {
            int vr = t >> 3, sl = t & 7;
            const unsigned short* vsrc = Vb + ((size_t)b * CC + vr) * HW + j0 + sl * 8;
            #pragma unroll
            for (int p = 0; p < 8; ++p)
                *(uint4*)(&Vs[vr + p * 32][sl * 8]) =
                    *(const uint4*)(vsrc + (size_t)p * 32 * HW);
        }
        __syncthreads();

        bf16x8 aq = *(const bf16x8*)(&Qs[w * 16 + li][lg * 8]);
        f32x4 S[4];
        #pragma unroll
        for (int j2 = 0; j2 < 4; ++j2) {
            bf16x8 bk = *(const bf16x8*)(&Ks[j2 * 16 + li][lg * 8]);
            S[j2] = __builtin_amdgcn_mfma_f32_16x16x32_bf16(
                aq, bk, (f32x4){0.f, 0.f, 0.f, 0.f}, 0, 0, 0);
        }

        float prow[4][4];
        #pragma unroll
        for (int r = 0; r < 4; ++r) {
            float t0 = S[0][r] * sc, t1 = S[1][r] * sc;
            float t2 = S[2][r] * sc, t3 = S[3][r] * sc;
            float mx = fmaxf(fmaxf(t0, t1), fmaxf(t2, t3));
            #pragma unroll
            for (int off = 1; off < 16; off <<= 1) mx = fmaxf(mx, __shfl_xor(mx, off));
            float mnew = fmaxf(m_run[r], mx);
            float al = exp2f(m_run[r] - mnew);
            float p0 = exp2f(t0 - mnew), p1 = exp2f(t1 - mnew);
            float p2 = exp2f(t2 - mnew), p3 = exp2f(t3 - mnew);
            float rs = p0 + p1 + p2 + p3;
            #pragma unroll
            for (int off = 1; off < 16; off <<= 1) rs += __shfl_xor(rs, off);
            l_run[r] = l_run[r] * al + rs;
            m_run[r] = mnew;
            prow[r][0] = p0; prow[r][1] = p1; prow[r][2] = p2; prow[r][3] = p3;
            if (li == 0) als[w * 16 + lg * 4 + r] = al;
        }
        #pragma unroll
        for (int r = 0; r < 4; ++r)
            #pragma unroll
            for (int j2 = 0; j2 < 4; ++j2)
                Ps[w * 16 + lg * 4 + r][j2 * 16 + li] = f2bf(prow[r][j2]);

        __syncthreads();

        bf16x8 bp[4][2];
        #pragma unroll
        for (int is = 0; is < 4; ++is)
            #pragma unroll
            for (int ks = 0; ks < 2; ++ks)
                bp[is][ks] = *(const bf16x8*)(&Ps[is * 16 + li][ks * 32 + lg * 8]);

        float ar[4];
        #pragma unroll
        for (int is = 0; is < 4; ++is) ar[is] = als[is * 16 + li];

        #pragma unroll
        for (int ct = 0; ct < 4; ++ct) {
            #pragma unroll
            for (int is = 0; is < 4; ++is) {
                #pragma unroll
                for (int r = 0; r < 4; ++r) acc[ct][is][r] *= ar[is];
            }
            #pragma unroll
            for (int ks = 0; ks < 2; ++ks) {
                bf16x8 av = *(const bf16x8*)(&Vs[w * 64 + ct * 16 + li][ks * 32 + lg * 8]);
                #pragma unroll
                for (int is = 0; is < 4; ++is)
                    acc[ct][is] = __builtin_amdgcn_mfma_f32_16x16x32_bf16(
                        av, bp[is][ks], acc[ct][is], 0, 0, 0);
            }
        }
    }

    if (li == 0) {
        #pragma unroll
        for (int r = 0; r < 4; ++r) lls[w * 16 + lg * 4 + r] = l_run[r];
    }
    __syncthreads();

    float invl[4];
    #pragma unroll
    for (int is = 0; is < 4; ++is) invl[is] = 1.f / lls[is * 16 + li];

    #pragma unroll
    for (int ct = 0; ct < 4; ++ct) {
        #pragma unroll
        for (int is = 0; is < 4; ++is) {
            #pragma unroll
            for (int r = 0; r < 4; ++r) {
                int c = w * 64 + ct * 16 + lg * 4 + r;
                ATT[((size_t)b * (4 * CC) + g * CC + c) * HW + i0 + is * 16 + li] =
                    acc[ct][is][r] * invl[is];
            }
        }
    }
}

// ---------------------------------------------------------------------------
// BatchNorm
// ---------------------------------------------------------------------------
__global__ __launch_bounds__(256) void bnstats(
    const float* __restrict__ out, float* __restrict__ mean,
    float* __restrict__ rstd) {
    const int c = blockIdx.x;
    float s = 0.f, s2 = 0.f;
    for (int e = threadIdx.x; e < BB * HW; e += 256) {
        int b = e / HW, i = e - b * HW;
        float v = out[((size_t)b * CC + c) * HW + i];
        s += v; s2 += v * v;
    }
    __shared__ float rs[256], rs2[256];
    rs[threadIdx.x] = s; rs2[threadIdx.x] = s2;
    __syncthreads();
    for (int st = 128; st > 0; st >>= 1) {
        if (threadIdx.x < st) {
            rs[threadIdx.x] += rs[threadIdx.x + st];
            rs2[threadIdx.x] += rs2[threadIdx.x + st];
        }
        __syncthreads();
    }
    if (threadIdx.x == 0) {
        const float n = (float)(BB * HW);
        float m = rs[0] / n;
        float var = rs2[0] / n - m * m;
        mean[c] = m;
        rstd[c] = rsqrtf(var + 1e-5f);
    }
}

__global__ __launch_bounds__(256) void bnapply(
    float* __restrict__ out, const float* __restrict__ mean,
    const float* __restrict__ rstd, const float* __restrict__ gamma,
    const float* __restrict__ beta) {
    size_t idx = (size_t)blockIdx.x * 256 + threadIdx.x;
    if (idx < (size_t)BB * CC * HW) {
        int c = (int)((idx / HW) % CC);
        out[idx] = (out[idx] - mean[c]) * rstd[c] * gamma[c] + beta[c];
    }
}

// ---------------------------------------------------------------------------
extern "C" void kernel_launch(void* const* d_in, const int* in_sizes, int n_in,
                              void* d_out, int out_size, void* d_ws, size_t ws_size,
                              hipStream_t stream) {
    const float* x     = (const float*)d_in[0];
    const float* wq1   = (const float*)d_in[1];
    const float* wq3   = (const float*)d_in[2];
    const float* wq5   = (const float*)d_in[3];
    const float* wq7   = (const float*)d_in[4];
    const float* wk    = (const float*)d_in[5];
    const float* wv    = (const float*)d_in[6];
    const float* wproj = (const float*)d_in[7];
    const float* gamma = (const float*)d_in[8];
    const float* beta  = (const float*)d_in[9];
    float* out = (float*)d_out;

    float* ATT  = (float*)d_ws;                              // B*4C*HW fp32
    float* mean = ATT + (size_t)BB * 4 * CC * HW;
    float* rstd = mean + CC;
    unsigned short* Kt  = (unsigned short*)(rstd + CC);      // [B][HW][32]
    unsigned short* Qt  = Kt + (size_t)BB * HW * 32;         // 4 x [B][HW][32]
    unsigned short* Vb  = Qt + (size_t)4 * BB * HW * 32;     // [B][C][HW]
    unsigned short* xT  = Vb + (size_t)BB * CC * HW;         // [B][HW][256]
    unsigned short* Wb3 = xT + (size_t)BB * HW * CC;         // [9][32][256]
    unsigned short* Wb5 = Wb3 + (size_t)9 * 32 * 256;        // [25][32][256]
    unsigned short* Wb7 = Wb5 + (size_t)25 * 32 * 256;       // [49][32][256]

    const size_t QSLICE = (size_t)BB * HW * 32;
    dim3 blk(256);

    // prep: weight repack + x transpose (bf16)
    wprep<<<dim3((9 * 8192 + 255) / 256), blk, 0, stream>>>(wq3, Wb3, 9);
    wprep<<<dim3((25 * 8192 + 255) / 256), blk, 0, stream>>>(wq5, Wb5, 25);
    wprep<<<dim3((49 * 8192 + 255) / 256), blk, 0, stream>>>(wq7, Wb7, 49);
    transpose_x<<<dim3(HW / 32, CC / 32, BB), blk, 0, stream>>>(x, xT);

    // K, Q1 (transposed bf16), V (bf16)
    gemm_qk32<<<dim3(HW / 64, BB), blk, 0, stream>>>(x, wk, Kt);
    gemm_qk32<<<dim3(HW / 64, BB), blk, 0, stream>>>(x, wq1, Qt);
    gemm1x1_v<<<dim3(CC / 16, HW / 64, BB), blk, 0, stream>>>(x, wv, Vb, CC, CC);

    // q3/q5/q7 MFMA im2col convs
    qconv_mfma<3><<<dim3(HW / 64, BB), blk, 0, stream>>>(xT, Wb3, Qt + 1 * QSLICE);
    qconv_mfma<5><<<dim3(HW / 64, BB), blk, 0, stream>>>(xT, Wb5, Qt + 2 * QSLICE);
    qconv_mfma<7><<<dim3(HW / 64, BB), blk, 0, stream>>>(xT, Wb7, Qt + 3 * QSLICE);

    // MFMA flash attention, all 4 branches
    flashmfma<<<dim3(HW / 64, BB, 4), blk, 0, stream>>>(Qt, Kt, Vb, ATT);

    // projection + residual -> d_out (pre-BN)
    gemm1x1<<<dim3(CC / 16, HW / 64, BB), blk, 0, stream>>>(ATT, wproj, x, out, 4 * CC, CC);

    // BatchNorm
    bnstats<<<dim3(CC), blk, 0, stream>>>(out, mean, rstd);
    bnapply<<<dim3((BB * CC * HW + 255) / 256), blk, 0, stream>>>(out, mean, rstd, gamma, beta);
}

// Round 6
// 582.541 us; speedup vs baseline: 103.3021x; 1.6256x over previous
//
#include <hip/hip_runtime.h>
#include <hip/hip_bf16.h>
#include <math.h>

#define HW 3136
#define WIDTH 56
#define CC 256
#define BB 4
#define RCH 32
#define SCLOG2E 0.2550437041556575f  // (1/sqrt(32)) * log2(e), folded into Q

using bf16x8 = __attribute__((ext_vector_type(8))) short;
using f32x4  = __attribute__((ext_vector_type(4))) float;

static __device__ __forceinline__ unsigned short f2bf(float f) {
    __hip_bfloat16 h = __float2bfloat16(f);
    return *reinterpret_cast<unsigned short*>(&h);
}

// ---------------------------------------------------------------------------
// 1x1 conv GEMM, bf16 out [b][co][hw]. Used for V.
// ---------------------------------------------------------------------------
__global__ __launch_bounds__(256) void gemm1x1_v(
    const float* __restrict__ in, const float* __restrict__ w,
    unsigned short* __restrict__ out, int Cin, int Cout) {
    const int tx = threadIdx.x & 15;
    const int ty = threadIdx.x >> 4;
    const int i0 = blockIdx.y * 64;
    const int co0 = blockIdx.x * 16;
    const int b = blockIdx.z;

    __shared__ float xs[32][64];
    __shared__ float wsl[16][33];

    float acc[4] = {0.f, 0.f, 0.f, 0.f};
    const float* inb = in + (size_t)b * Cin * HW;

    for (int c0 = 0; c0 < Cin; c0 += 32) {
        #pragma unroll
        for (int k = 0; k < 8; ++k) {
            int e = threadIdx.x + k * 256;
            int r = e >> 6, col = e & 63;
            xs[r][col] = inb[(size_t)(c0 + r) * HW + i0 + col];
        }
        #pragma unroll
        for (int k = 0; k < 2; ++k) {
            int e = threadIdx.x + k * 256;
            int r = e >> 5, col = e & 31;
            wsl[r][col] = w[(size_t)(co0 + r) * Cin + c0 + col];
        }
        __syncthreads();
        #pragma unroll
        for (int c = 0; c < 32; ++c) {
            float wv = wsl[ty][c];
            #pragma unroll
            for (int u = 0; u < 4; ++u)
                acc[u] += wv * xs[c][tx + 16 * u];
        }
        __syncthreads();
    }

    size_t obase = ((size_t)b * Cout + co0 + ty) * HW + i0 + tx;
    #pragma unroll
    for (int u = 0; u < 4; ++u)
        out[obase + 16 * u] = f2bf(acc[u]);
}

// ---------------------------------------------------------------------------
// 1x1 conv, Cout=32, TRANSPOSED bf16 out: outt[b][hw][32]. K (oscale=1) and
// Q1 (oscale=SCLOG2E, so flash scores come out pre-scaled for exp2).
// ---------------------------------------------------------------------------
__global__ __launch_bounds__(256) void gemm_qk32(
    const float* __restrict__ in, const float* __restrict__ w,
    unsigned short* __restrict__ outt, float oscale) {
    const int i = threadIdx.x & 63;
    const int cog = threadIdx.x >> 6;
    const int i0 = blockIdx.x * 64;
    const int b = blockIdx.y;

    __shared__ float xs[32][64];
    __shared__ float wsl[32][33];

    float acc[8] = {0.f,0.f,0.f,0.f,0.f,0.f,0.f,0.f};
    const float* inb = in + (size_t)b * CC * HW;

    for (int c0 = 0; c0 < CC; c0 += 32) {
        #pragma unroll
        for (int k = 0; k < 8; ++k) {
            int e = threadIdx.x + k * 256;
            int r = e >> 6, col = e & 63;
            xs[r][col] = inb[(size_t)(c0 + r) * HW + i0 + col];
        }
        #pragma unroll
        for (int k = 0; k < 4; ++k) {
            int e = threadIdx.x + k * 256;
            int r = e >> 5, col = e & 31;
            wsl[r][col] = w[(size_t)r * CC + c0 + col];
        }
        __syncthreads();
        #pragma unroll
        for (int c = 0; c < 32; ++c) {
            float xv = xs[c][i];
            #pragma unroll
            for (int u = 0; u < 8; ++u)
                acc[u] += wsl[cog * 8 + u][c] * xv;
        }
        __syncthreads();
    }
    unsigned int pk[4];
    #pragma unroll
    for (int u = 0; u < 4; ++u)
        pk[u] = (unsigned int)f2bf(acc[2 * u] * oscale) |
                ((unsigned int)f2bf(acc[2 * u + 1] * oscale) << 16);
    *(uint4*)(outt + ((size_t)b * HW + i0 + i) * 32 + cog * 8) = *(uint4*)pk;
}

// ---------------------------------------------------------------------------
// x transpose + bf16: xT[b][hw][c]. grid (HW/32, C/32, B), block 256 (32x8).
// ---------------------------------------------------------------------------
__global__ __launch_bounds__(256) void transpose_x(
    const float* __restrict__ x, unsigned short* __restrict__ xT) {
    __shared__ unsigned short tile[32][33];
    const int b = blockIdx.z;
    const int i0 = blockIdx.x * 32, c0 = blockIdx.y * 32;
    const int tx = threadIdx.x & 31, ty = threadIdx.x >> 5;
    #pragma unroll
    for (int k = 0; k < 4; ++k)
        tile[ty + k * 8][tx] = f2bf(x[((size_t)b * CC + c0 + ty + k * 8) * HW + i0 + tx]);
    __syncthreads();
    #pragma unroll
    for (int k = 0; k < 4; ++k)
        xT[((size_t)b * HW + i0 + ty + k * 8) * 256 + c0 + tx] = tile[tx][ty + k * 8];
}

// ---------------------------------------------------------------------------
// Weight repack: Wb[t][r][c] bf16 from w[r][c][t] fp32 (q-conv weights).
// ---------------------------------------------------------------------------
__global__ __launch_bounds__(256) void wprep(
    const float* __restrict__ w, unsigned short* __restrict__ Wb, int KT) {
    int e = blockIdx.x * 256 + threadIdx.x;
    if (e < KT * 32 * 256) {
        int c = e & 255, r = (e >> 8) & 31, t = e >> 13;
        Wb[e] = f2bf(w[((size_t)r * 256 + c) * KT + t]);
    }
}

// simple fp32 -> bf16 cast (wproj)
__global__ __launch_bounds__(256) void cvt_bf16(
    const float* __restrict__ src, unsigned short* __restrict__ dst, int n) {
    int e = blockIdx.x * 256 + threadIdx.x;
    if (e < n) dst[e] = f2bf(src[e]);
}

// ---------------------------------------------------------------------------
// MFMA im2col q-conv body (shared LDS passed in). Output scaled by SCLOG2E.
// ---------------------------------------------------------------------------
template <int KS>
static __device__ __forceinline__ void qconv_body(
    const unsigned short* __restrict__ xT,  // [b][hw][256] bf16
    const unsigned short* __restrict__ Wb,  // [KT][32][256] bf16
    unsigned short* __restrict__ q,         // [b][hw][32] bf16
    unsigned short (*xs)[40]) {
    constexpr int P = (KS - 1) / 2;
    constexpr int KT = KS * KS;
    constexpr int ROWS = 64 + 114 * P;
    const int b = blockIdx.y;
    const int i0 = blockIdx.x * 64;
    const int t = threadIdx.x;
    const int lane = t & 63;
    const int w = t >> 6;
    const int li = lane & 15;
    const int lg = lane >> 4;

    const int base = i0 - P * 57;
    const int mycol = (i0 + w * 16 + li) % WIDTH;

    f32x4 acc[2];
    acc[0] = (f32x4){0.f, 0.f, 0.f, 0.f};
    acc[1] = (f32x4){0.f, 0.f, 0.f, 0.f};

    const unsigned short* xTb = xT + (size_t)b * HW * 256;

    for (int c0 = 0; c0 < 256; c0 += 32) {
        __syncthreads();
        for (int e = t; e < ROWS * 4; e += 256) {
            int row = e >> 2, cs = e & 3;
            int gidx = base + row;
            uint4 val = make_uint4(0, 0, 0, 0);
            if (gidx >= 0 && gidx < HW)
                val = *(const uint4*)(xTb + (size_t)gidx * 256 + c0 + cs * 8);
            *(uint4*)(&xs[row][cs * 8]) = val;
        }
        __syncthreads();

        #pragma unroll
        for (int tap = 0; tap < KT; ++tap) {
            const int dx = tap % KS - P;
            const int poff = (tap / KS) * WIDTH + tap % KS;
            bf16x8 a = *(const bf16x8*)(&xs[w * 16 + li + poff][lg * 8]);
            if ((unsigned)(mycol + dx) >= (unsigned)WIDTH)
                a = (bf16x8){0, 0, 0, 0, 0, 0, 0, 0};
            const unsigned short* wrow =
                Wb + (size_t)tap * 32 * 256 + c0 + lg * 8;
            bf16x8 b0 = *(const bf16x8*)(wrow + (size_t)li * 256);
            bf16x8 b1 = *(const bf16x8*)(wrow + (size_t)(16 + li) * 256);
            acc[0] = __builtin_amdgcn_mfma_f32_16x16x32_bf16(a, b0, acc[0], 0, 0, 0);
            acc[1] = __builtin_amdgcn_mfma_f32_16x16x32_bf16(a, b1, acc[1], 0, 0, 0);
        }
    }

    unsigned short* qb = q + ((size_t)b * HW + i0 + w * 16 + lg * 4) * 32;
    #pragma unroll
    for (int rs = 0; rs < 2; ++rs)
        #pragma unroll
        for (int r = 0; r < 4; ++r)
            qb[(size_t)r * 32 + rs * 16 + li] = f2bf(acc[rs][r] * SCLOG2E);
}

// All three q-convs in one launch: grid (HW/64, B, 3), z picks kernel size.
__global__ __launch_bounds__(256) void qconv_all(
    const unsigned short* __restrict__ xT,
    const unsigned short* __restrict__ Wb3,
    const unsigned short* __restrict__ Wb5,
    const unsigned short* __restrict__ Wb7,
    unsigned short* __restrict__ Qt) {
    __shared__ unsigned short xs[406][40];  // sized for KS=7
    const size_t QSLICE = (size_t)BB * HW * 32;
    if (blockIdx.z == 0)      qconv_body<3>(xT, Wb3, Qt + 1 * QSLICE, xs);
    else if (blockIdx.z == 1) qconv_body<5>(xT, Wb5, Qt + 2 * QSLICE, xs);
    else                      qconv_body<7>(xT, Wb7, Qt + 3 * QSLICE, xs);
}

// ---------------------------------------------------------------------------
// MFMA flash attention, v2: no online max (scores bounded: |logit*log2e|<~40,
// exp2/fp32 have huge headroom; relative precision identical), K/V/Q read
// directly from global (L2-resident), only the P transpose goes through LDS.
// Ps rows padded to 72 elems = 144B: MUST be a 16B multiple -- the bf16x8
// fragment reads are ds_read_b128 which require 16B-aligned addresses.
// grid: (HW/64, B, 4), block 256 (4 waves). Wave w: QK+softmax for i-strip
// w*16..+15, PV for channel strip w*64..+63. Output ATT bf16 [b][g*256+c][hw].
// ---------------------------------------------------------------------------
__global__ __launch_bounds__(256) void flashmfma(
    const unsigned short* __restrict__ Qt, const unsigned short* __restrict__ Kt,
    const unsigned short* __restrict__ Vb, unsigned short* __restrict__ ATTb) {
    const int b = blockIdx.y, g = blockIdx.z;
    const int i0 = blockIdx.x * 64;
    const int t = threadIdx.x;
    const int lane = t & 63;
    const int w = t >> 6;
    const int lg = lane >> 4;
    const int li = lane & 15;

    __shared__ __align__(16) unsigned short Ps[64][72];  // 144B rows (16B mult)
    __shared__ float lls[64];

    // Q fragment for this wave's i-strip, loop-invariant (Q pre-scaled)
    const bf16x8 aq = *(const bf16x8*)(
        Qt + ((size_t)(g * BB + b) * HW + i0 + w * 16 + li) * 32 + lg * 8);

    const f32x4 z4 = (f32x4){0.f, 0.f, 0.f, 0.f};
    f32x4 acc[4][4];
    #pragma unroll
    for (int ct = 0; ct < 4; ++ct)
        #pragma unroll
        for (int is = 0; is < 4; ++is) acc[ct][is] = z4;

    float lsum[4] = {0.f, 0.f, 0.f, 0.f};

    const unsigned short* Kb = Kt + (size_t)b * HW * 32;
    const unsigned short* Vw = Vb + ((size_t)b * CC + w * 64) * HW;

    for (int jt = 0; jt < HW / 64; ++jt) {
        const int j0 = jt * 64;

        // ---- QK^T (K frags from global, fully coalesced)
        f32x4 S[4];
        #pragma unroll
        for (int j2 = 0; j2 < 4; ++j2) {
            bf16x8 bk = *(const bf16x8*)(Kb + (size_t)(j0 + j2 * 16 + li) * 32 + lg * 8);
            S[j2] = __builtin_amdgcn_mfma_f32_16x16x32_bf16(aq, bk, z4, 0, 0, 0);
        }

        // ---- softmax numerator: p = exp2(s) (no max subtraction needed)
        unsigned int pk0[4], pk1[4];
        #pragma unroll
        for (int r = 0; r < 4; ++r) {
            float p0 = __builtin_amdgcn_exp2f(S[0][r]);
            float p1 = __builtin_amdgcn_exp2f(S[1][r]);
            float p2 = __builtin_amdgcn_exp2f(S[2][r]);
            float p3 = __builtin_amdgcn_exp2f(S[3][r]);
            lsum[r] += (p0 + p1) + (p2 + p3);
            asm("v_cvt_pk_bf16_f32 %0, %1, %2" : "=v"(pk0[r]) : "v"(p0), "v"(p1));
            asm("v_cvt_pk_bf16_f32 %0, %1, %2" : "=v"(pk1[r]) : "v"(p2), "v"(p3));
        }

        __syncthreads();  // prev tile's Ps reads complete
        #pragma unroll
        for (int r = 0; r < 4; ++r) {
            const int row = w * 16 + lg * 4 + r;
            Ps[row][li]      = (unsigned short)pk0[r];
            Ps[row][16 + li] = (unsigned short)(pk0[r] >> 16);
            Ps[row][32 + li] = (unsigned short)pk1[r];
            Ps[row][48 + li] = (unsigned short)(pk1[r] >> 16);
        }
        __syncthreads();  // Ps ready

        // ---- PV: V frags straight from global (L2), P from LDS
        bf16x8 bp[4][2];
        #pragma unroll
        for (int is = 0; is < 4; ++is)
            #pragma unroll
            for (int ks = 0; ks < 2; ++ks)
                bp[is][ks] = *(const bf16x8*)(&Ps[is * 16 + li][ks * 32 + lg * 8]);

        #pragma unroll
        for (int ct = 0; ct < 4; ++ct) {
            #pragma unroll
            for (int ks = 0; ks < 2; ++ks) {
                bf16x8 av = *(const bf16x8*)(
                    Vw + (size_t)(ct * 16 + li) * HW + j0 + ks * 32 + lg * 8);
                #pragma unroll
                for (int is = 0; is < 4; ++is)
                    acc[ct][is] = __builtin_amdgcn_mfma_f32_16x16x32_bf16(
                        av, bp[is][ks], acc[ct][is], 0, 0, 0);
            }
        }
    }

    // row-sum reduce over the 16 li lanes (j-distribution), once
    #pragma unroll
    for (int r = 0; r < 4; ++r) {
        float s = lsum[r];
        #pragma unroll
        for (int off = 1; off < 16; off <<= 1) s += __shfl_xor(s, off);
        if (li == 0) lls[w * 16 + lg * 4 + r] = s;
    }
    __syncthreads();

    float invl[4];
    #pragma unroll
    for (int is = 0; is < 4; ++is) invl[is] = 1.f / lls[is * 16 + li];

    #pragma unroll
    for (int ct = 0; ct < 4; ++ct)
        #pragma unroll
        for (int is = 0; is < 4; ++is)
            #pragma unroll
            for (int r = 0; r < 4; ++r) {
                int c = w * 64 + ct * 16 + lg * 4 + r;
                ATTb[((size_t)b * (4 * CC) + g * CC + c) * HW + i0 + is * 16 + li] =
                    f2bf(acc[ct][is][r] * invl[is]);
            }
}

// ---------------------------------------------------------------------------
// MFMA projection: out[b][co][i] = sum_{cin<1024} wproj[co][cin]*ATT[cin][i]+x.
// grid (HW/32, B), block 256 (4 waves, wave = 64-co strip). A (ATT) is
// LDS-transposed per 64-cin chunk; W frags stream from L2.
// As rows padded to 72 (144B, 16B multiple) for aligned ds_read_b128.
// ---------------------------------------------------------------------------
__global__ __launch_bounds__(256) void gemm_proj(
    const unsigned short* __restrict__ ATTb, const unsigned short* __restrict__ Wpb,
    const float* __restrict__ x, float* __restrict__ out) {
    const int b = blockIdx.y;
    const int i0 = blockIdx.x * 32;
    const int t = threadIdx.x;
    const int lane = t & 63;
    const int w = t >> 6;
    const int lg = lane >> 4;
    const int li = lane & 15;

    __shared__ __align__(16) unsigned short As[32][72];  // [i][cin-chunk]

    const f32x4 z4 = (f32x4){0.f, 0.f, 0.f, 0.f};
    f32x4 acc[4][2];
    #pragma unroll
    for (int ct = 0; ct < 4; ++ct) { acc[ct][0] = z4; acc[ct][1] = z4; }

    for (int k0 = 0; k0 < 1024; k0 += 64) {
        __syncthreads();
        {
            int row = t >> 2, seg = t & 3;  // row = cin offset, seg = 8-i chunk
            uint4 v = *(const uint4*)(
                ATTb + ((size_t)b * 1024 + k0 + row) * HW + i0 + seg * 8);
            const unsigned short* sv = (const unsigned short*)&v;
            #pragma unroll
            for (int u = 0; u < 8; ++u) As[seg * 8 + u][row] = sv[u];
        }
        __syncthreads();

        #pragma unroll
        for (int k2 = 0; k2 < 2; ++k2) {
            bf16x8 afr[2];
            #pragma unroll
            for (int is = 0; is < 2; ++is)
                afr[is] = *(const bf16x8*)(&As[is * 16 + li][k2 * 32 + lg * 8]);
            #pragma unroll
            for (int ct = 0; ct < 4; ++ct) {
                bf16x8 wf = *(const bf16x8*)(
                    Wpb + (size_t)(w * 64 + ct * 16 + li) * 1024 + k0 + k2 * 32 + lg * 8);
                #pragma unroll
                for (int is = 0; is < 2; ++is)
                    acc[ct][is] = __builtin_amdgcn_mfma_f32_16x16x32_bf16(
                        wf, afr[is], acc[ct][is], 0, 0, 0);
            }
        }
    }

    #pragma unroll
    for (int ct = 0; ct < 4; ++ct)
        #pragma unroll
        for (int is = 0; is < 2; ++is)
            #pragma unroll
            for (int r = 0; r < 4; ++r) {
                int co = w * 64 + ct * 16 + lg * 4 + r;
                size_t o = ((size_t)b * CC + co) * HW + i0 + is * 16 + li;
                out[o] = acc[ct][is][r] + x[o];
            }
}

// ---------------------------------------------------------------------------
// BatchNorm
// ---------------------------------------------------------------------------
__global__ __launch_bounds__(256) void bnstats(
    const float* __restrict__ out, float* __restrict__ mean,
    float* __restrict__ rstd) {
    const int c = blockIdx.x;
    float s = 0.f, s2 = 0.f;
    for (int e = threadIdx.x; e < BB * HW; e += 256) {
        int b = e / HW, i = e - b * HW;
        float v = out[((size_t)b * CC + c) * HW + i];
        s += v; s2 += v * v;
    }
    __shared__ float rs[256], rs2[256];
    rs[threadIdx.x] = s; rs2[threadIdx.x] = s2;
    __syncthreads();
    for (int st = 128; st > 0; st >>= 1) {
        if (threadIdx.x < st) {
            rs[threadIdx.x] += rs[threadIdx.x + st];
            rs2[threadIdx.x] += rs2[threadIdx.x + st];
        }
        __syncthreads();
    }
    if (threadIdx.x == 0) {
        const float n = (float)(BB * HW);
        float m = rs[0] / n;
        float var = rs2[0] / n - m * m;
        mean[c] = m;
        rstd[c] = rsqrtf(var + 1e-5f);
    }
}

__global__ __launch_bounds__(256) void bnapply(
    float* __restrict__ out, const float* __restrict__ mean,
    const float* __restrict__ rstd, const float* __restrict__ gamma,
    const float* __restrict__ beta) {
    size_t idx = (size_t)blockIdx.x * 256 + threadIdx.x;
    if (idx < (size_t)BB * CC * HW) {
        int c = (int)((idx / HW) % CC);
        out[idx] = (out[idx] - mean[c]) * rstd[c] * gamma[c] + beta[c];
    }
}

// ---------------------------------------------------------------------------
extern "C" void kernel_launch(void* const* d_in, const int* in_sizes, int n_in,
                              void* d_out, int out_size, void* d_ws, size_t ws_size,
                              hipStream_t stream) {
    const float* x     = (const float*)d_in[0];
    const float* wq1   = (const float*)d_in[1];
    const float* wq3   = (const float*)d_in[2];
    const float* wq5   = (const float*)d_in[3];
    const float* wq7   = (const float*)d_in[4];
    const float* wk    = (const float*)d_in[5];
    const float* wv    = (const float*)d_in[6];
    const float* wproj = (const float*)d_in[7];
    const float* gamma = (const float*)d_in[8];
    const float* beta  = (const float*)d_in[9];
    float* out = (float*)d_out;

    unsigned short* ATTb = (unsigned short*)d_ws;            // [B][1024][HW]
    unsigned short* Kt   = ATTb + (size_t)BB * 4 * CC * HW;  // [B][HW][32]
    unsigned short* Qt   = Kt + (size_t)BB * HW * 32;        // 4 x [B][HW][32]
    unsigned short* Vb   = Qt + (size_t)4 * BB * HW * 32;    // [B][C][HW]
    unsigned short* xT   = Vb + (size_t)BB * CC * HW;        // [B][HW][256]
    unsigned short* Wb3  = xT + (size_t)BB * HW * CC;        // [9][32][256]
    unsigned short* Wb5  = Wb3 + (size_t)9 * 32 * 256;
    unsigned short* Wb7  = Wb5 + (size_t)25 * 32 * 256;
    unsigned short* Wpb  = Wb7 + (size_t)49 * 32 * 256;      // [256][1024]
    float* mean = (float*)(Wpb + (size_t)256 * 1024);
    float* rstd = mean + CC;

    dim3 blk(256);

    // prep: weight repacks + x transpose (bf16)
    wprep<<<dim3((9 * 8192 + 255) / 256), blk, 0, stream>>>(wq3, Wb3, 9);
    wprep<<<dim3((25 * 8192 + 255) / 256), blk, 0, stream>>>(wq5, Wb5, 25);
    wprep<<<dim3((49 * 8192 + 255) / 256), blk, 0, stream>>>(wq7, Wb7, 49);
    cvt_bf16<<<dim3((256 * 1024 + 255) / 256), blk, 0, stream>>>(wproj, Wpb, 256 * 1024);
    transpose_x<<<dim3(HW / 32, CC / 32, BB), blk, 0, stream>>>(x, xT);

    // K (unscaled), Q1 (scaled), V
    gemm_qk32<<<dim3(HW / 64, BB), blk, 0, stream>>>(x, wk, Kt, 1.0f);
    gemm_qk32<<<dim3(HW / 64, BB), blk, 0, stream>>>(x, wq1, Qt, SCLOG2E);
    gemm1x1_v<<<dim3(CC / 16, HW / 64, BB), blk, 0, stream>>>(x, wv, Vb, CC, CC);

    // q3/q5/q7 fused MFMA im2col convs (one launch, 588 blocks)
    qconv_all<<<dim3(HW / 64, BB, 3), blk, 0, stream>>>(xT, Wb3, Wb5, Wb7, Qt);

    // MFMA flash attention, all 4 branches -> bf16 ATT
    flashmfma<<<dim3(HW / 64, BB, 4), blk, 0, stream>>>(Qt, Kt, Vb, ATTb);

    // MFMA projection + residual -> d_out (pre-BN, fp32)
    gemm_proj<<<dim3(HW / 32, BB), blk, 0, stream>>>(ATTb, Wpb, x, out);

    // BatchNorm
    bnstats<<<dim3(CC), blk, 0, stream>>>(out, mean, rstd);
    bnapply<<<dim3((BB * CC * HW + 255) / 256), blk, 0, stream>>>(out, mean, rstd, gamma, beta);
}

// Round 9
// 494.762 us; speedup vs baseline: 121.6296x; 1.1774x over previous
//
#include <hip/hip_runtime.h>
#include <hip/hip_bf16.h>
#include <math.h>

#define HW 3136
#define WIDTH 56
#define CC 256
#define BB 4
#define RCH 32
#define NJT (HW / 64)
#define SCLOG2E 0.2550437041556575f  // (1/sqrt(32)) * log2(e), folded into Q

using bf16x8 = __attribute__((ext_vector_type(8))) short;
using f32x4  = __attribute__((ext_vector_type(4))) float;

static __device__ __forceinline__ unsigned short f2bf(float f) {
    __hip_bfloat16 h = __float2bfloat16(f);
    return *reinterpret_cast<unsigned short*>(&h);
}

// ---------------------------------------------------------------------------
// Fused weight prep: q-conv repacks (Wb[t][r][c]), wproj cast, wk/wq1 cast,
// wv cast. One launch.
// ---------------------------------------------------------------------------
__global__ __launch_bounds__(256) void prep_weights(
    const float* __restrict__ wq3, const float* __restrict__ wq5,
    const float* __restrict__ wq7, const float* __restrict__ wproj,
    const float* __restrict__ wk, const float* __restrict__ wq1,
    const float* __restrict__ wv,
    unsigned short* __restrict__ Wb3, unsigned short* __restrict__ Wb5,
    unsigned short* __restrict__ Wb7, unsigned short* __restrict__ Wpb,
    unsigned short* __restrict__ Wkq, unsigned short* __restrict__ Wvb) {
    int e = blockIdx.x * 256 + threadIdx.x;
    if (e < 73728) {  // wq3: KT=9
        int c = e & 255, r = (e >> 8) & 31, t = e >> 13;
        Wb3[e] = f2bf(wq3[((size_t)r * 256 + c) * 9 + t]);
    } else if (e < 278528) {  // wq5: KT=25
        int i = e - 73728;
        int c = i & 255, r = (i >> 8) & 31, t = i >> 13;
        Wb5[i] = f2bf(wq5[((size_t)r * 256 + c) * 25 + t]);
    } else if (e < 679936) {  // wq7: KT=49
        int i = e - 278528;
        int c = i & 255, r = (i >> 8) & 31, t = i >> 13;
        Wb7[i] = f2bf(wq7[((size_t)r * 256 + c) * 49 + t]);
    } else if (e < 942080) {  // wproj [256][1024]
        int i = e - 679936;
        Wpb[i] = f2bf(wproj[i]);
    } else if (e < 958464) {  // wk | wq1, [2][32][256]
        int i = e - 942080;
        Wkq[i] = f2bf(i < 8192 ? wk[i] : wq1[i - 8192]);
    } else if (e < 1024000) {  // wv [256][256]
        int i = e - 958464;
        Wvb[i] = f2bf(wv[i]);
    }
}

// ---------------------------------------------------------------------------
// x transpose + bf16: xT[b][hw][c]. grid (HW/32, C/32, B), block 256 (32x8).
// ---------------------------------------------------------------------------
__global__ __launch_bounds__(256) void transpose_x(
    const float* __restrict__ x, unsigned short* __restrict__ xT) {
    __shared__ unsigned short tile[32][33];
    const int b = blockIdx.z;
    const int i0 = blockIdx.x * 32, c0 = blockIdx.y * 32;
    const int tx = threadIdx.x & 31, ty = threadIdx.x >> 5;
    #pragma unroll
    for (int k = 0; k < 4; ++k)
        tile[ty + k * 8][tx] = f2bf(x[((size_t)b * CC + c0 + ty + k * 8) * HW + i0 + tx]);
    __syncthreads();
    #pragma unroll
    for (int k = 0; k < 4; ++k)
        xT[((size_t)b * HW + i0 + ty + k * 8) * 256 + c0 + tx] = tile[tx][ty + k * 8];
}

// ---------------------------------------------------------------------------
// K / Q1 via MFMA, no LDS, no barriers. outt[b][hw][32] bf16 (Q pre-scaled).
// grid (HW/64, B, 2): z=0 -> K (scale 1), z=1 -> Q1 (scale SCLOG2E).
// ---------------------------------------------------------------------------
__global__ __launch_bounds__(256) void qk32_mfma(
    const unsigned short* __restrict__ xT, const unsigned short* __restrict__ Wkq,
    unsigned short* __restrict__ Kt, unsigned short* __restrict__ Qt) {
    const int b = blockIdx.y, z = blockIdx.z;
    const int i0 = blockIdx.x * 64;
    const int t = threadIdx.x;
    const int lane = t & 63, w = t >> 6, lg = lane >> 4, li = lane & 15;

    unsigned short* outp = z == 0 ? Kt : Qt;
    const float osc = z == 0 ? 1.0f : SCLOG2E;
    const unsigned short* wb = Wkq + z * 8192;
    const unsigned short* xb = xT + ((size_t)b * HW + i0 + w * 16 + li) * 256;

    const f32x4 z4 = (f32x4){0.f, 0.f, 0.f, 0.f};
    f32x4 acc[2] = {z4, z4};

    for (int c0 = 0; c0 < 256; c0 += 32) {
        bf16x8 ax = *(const bf16x8*)(xb + c0 + lg * 8);
        #pragma unroll
        for (int rs = 0; rs < 2; ++rs) {
            bf16x8 bw = *(const bf16x8*)(wb + (size_t)(rs * 16 + li) * 256 + c0 + lg * 8);
            acc[rs] = __builtin_amdgcn_mfma_f32_16x16x32_bf16(ax, bw, acc[rs], 0, 0, 0);
        }
    }
    unsigned short* qb = outp + ((size_t)b * HW + i0 + w * 16 + lg * 4) * 32;
    #pragma unroll
    for (int rs = 0; rs < 2; ++rs)
        #pragma unroll
        for (int r = 0; r < 4; ++r)
            qb[(size_t)r * 32 + rs * 16 + li] = f2bf(acc[rs][r] * osc);
}

// ---------------------------------------------------------------------------
// V via MFMA, no LDS, no barriers. V[b][co][hw] bf16.
// grid (HW/32, B). Wave w owns co strip w*64..+63.
// ---------------------------------------------------------------------------
__global__ __launch_bounds__(256) void v_mfma(
    const unsigned short* __restrict__ xT, const unsigned short* __restrict__ Wvb,
    unsigned short* __restrict__ Vb) {
    const int b = blockIdx.y;
    const int i0 = blockIdx.x * 32;
    const int t = threadIdx.x;
    const int lane = t & 63, w = t >> 6, lg = lane >> 4, li = lane & 15;

    const f32x4 z4 = (f32x4){0.f, 0.f, 0.f, 0.f};
    f32x4 acc[4][2];
    #pragma unroll
    for (int ct = 0; ct < 4; ++ct) { acc[ct][0] = z4; acc[ct][1] = z4; }

    const unsigned short* xb = xT + (size_t)b * HW * 256;

    for (int c0 = 0; c0 < 256; c0 += 32) {
        bf16x8 bx[2];
        #pragma unroll
        for (int is = 0; is < 2; ++is)
            bx[is] = *(const bf16x8*)(xb + (size_t)(i0 + is * 16 + li) * 256 + c0 + lg * 8);
        #pragma unroll
        for (int ct = 0; ct < 4; ++ct) {
            bf16x8 aw = *(const bf16x8*)(
                Wvb + (size_t)(w * 64 + ct * 16 + li) * 256 + c0 + lg * 8);
            #pragma unroll
            for (int is = 0; is < 2; ++is)
                acc[ct][is] = __builtin_amdgcn_mfma_f32_16x16x32_bf16(
                    aw, bx[is], acc[ct][is], 0, 0, 0);
        }
    }
    #pragma unroll
    for (int ct = 0; ct < 4; ++ct)
        #pragma unroll
        for (int is = 0; is < 2; ++is)
            #pragma unroll
            for (int r = 0; r < 4; ++r)
                Vb[((size_t)b * CC + w * 64 + ct * 16 + lg * 4 + r) * HW +
                   i0 + is * 16 + li] = f2bf(acc[ct][is][r]);
}

// ---------------------------------------------------------------------------
// MFMA im2col q-conv body (shared LDS passed in). Output scaled by SCLOG2E.
// ---------------------------------------------------------------------------
template <int KS>
static __device__ __forceinline__ void qconv_body(
    const unsigned short* __restrict__ xT,  // [b][hw][256] bf16
    const unsigned short* __restrict__ Wb,  // [KT][32][256] bf16
    unsigned short* __restrict__ q,         // [b][hw][32] bf16
    unsigned short (*xs)[40]) {
    constexpr int P = (KS - 1) / 2;
    constexpr int KT = KS * KS;
    constexpr int ROWS = 64 + 114 * P;
    const int b = blockIdx.y;
    const int i0 = blockIdx.x * 64;
    const int t = threadIdx.x;
    const int lane = t & 63;
    const int w = t >> 6;
    const int li = lane & 15;
    const int lg = lane >> 4;

    const int base = i0 - P * 57;
    const int mycol = (i0 + w * 16 + li) % WIDTH;

    f32x4 acc[2];
    acc[0] = (f32x4){0.f, 0.f, 0.f, 0.f};
    acc[1] = (f32x4){0.f, 0.f, 0.f, 0.f};

    const unsigned short* xTb = xT + (size_t)b * HW * 256;

    for (int c0 = 0; c0 < 256; c0 += 32) {
        __syncthreads();
        for (int e = t; e < ROWS * 4; e += 256) {
            int row = e >> 2, cs = e & 3;
            int gidx = base + row;
            uint4 val = make_uint4(0, 0, 0, 0);
            if (gidx >= 0 && gidx < HW)
                val = *(const uint4*)(xTb + (size_t)gidx * 256 + c0 + cs * 8);
            *(uint4*)(&xs[row][cs * 8]) = val;
        }
        __syncthreads();

        #pragma unroll
        for (int tap = 0; tap < KT; ++tap) {
            const int dx = tap % KS - P;
            const int poff = (tap / KS) * WIDTH + tap % KS;
            bf16x8 a = *(const bf16x8*)(&xs[w * 16 + li + poff][lg * 8]);
            if ((unsigned)(mycol + dx) >= (unsigned)WIDTH)
                a = (bf16x8){0, 0, 0, 0, 0, 0, 0, 0};
            const unsigned short* wrow =
                Wb + (size_t)tap * 32 * 256 + c0 + lg * 8;
            bf16x8 b0 = *(const bf16x8*)(wrow + (size_t)li * 256);
            bf16x8 b1 = *(const bf16x8*)(wrow + (size_t)(16 + li) * 256);
            acc[0] = __builtin_amdgcn_mfma_f32_16x16x32_bf16(a, b0, acc[0], 0, 0, 0);
            acc[1] = __builtin_amdgcn_mfma_f32_16x16x32_bf16(a, b1, acc[1], 0, 0, 0);
        }
    }

    unsigned short* qb = q + ((size_t)b * HW + i0 + w * 16 + lg * 4) * 32;
    #pragma unroll
    for (int rs = 0; rs < 2; ++rs)
        #pragma unroll
        for (int r = 0; r < 4; ++r)
            qb[(size_t)r * 32 + rs * 16 + li] = f2bf(acc[rs][r] * SCLOG2E);
}

// All three q-convs in one launch: grid (HW/64, B, 3), z picks kernel size.
__global__ __launch_bounds__(256) void qconv_all(
    const unsigned short* __restrict__ xT,
    const unsigned short* __restrict__ Wb3,
    const unsigned short* __restrict__ Wb5,
    const unsigned short* __restrict__ Wb7,
    unsigned short* __restrict__ Qt) {
    __shared__ unsigned short xs[406][40];  // sized for KS=7
    const size_t QSLICE = (size_t)BB * HW * 32;
    if (blockIdx.z == 0)      qconv_body<3>(xT, Wb3, Qt + 1 * QSLICE, xs);
    else if (blockIdx.z == 1) qconv_body<5>(xT, Wb5, Qt + 2 * QSLICE, xs);
    else                      qconv_body<7>(xT, Wb7, Qt + 3 * QSLICE, xs);
}

// ---------------------------------------------------------------------------
// MFMA flash attention — VERBATIM round-6 version (verified passing, 260us):
// no online max; K/V/Q read directly from global (L2-resident); single Ps
// buffer with TWO barriers per tile; no prefetch, no setprio.
// grid: (HW/64, B, 4), block 256 (4 waves). Wave w: QK+softmax for i-strip
// w*16..+15, PV for channel strip w*64..+63. Output ATT bf16 [b][g*256+c][hw].
// ---------------------------------------------------------------------------
__global__ __launch_bounds__(256) void flashmfma(
    const unsigned short* __restrict__ Qt, const unsigned short* __restrict__ Kt,
    const unsigned short* __restrict__ Vb, unsigned short* __restrict__ ATTb) {
    const int b = blockIdx.y, g = blockIdx.z;
    const int i0 = blockIdx.x * 64;
    const int t = threadIdx.x;
    const int lane = t & 63;
    const int w = t >> 6;
    const int lg = lane >> 4;
    const int li = lane & 15;

    __shared__ __align__(16) unsigned short Ps[64][72];  // 144B rows (16B mult)
    __shared__ float lls[64];

    // Q fragment for this wave's i-strip, loop-invariant (Q pre-scaled)
    const bf16x8 aq = *(const bf16x8*)(
        Qt + ((size_t)(g * BB + b) * HW + i0 + w * 16 + li) * 32 + lg * 8);

    const f32x4 z4 = (f32x4){0.f, 0.f, 0.f, 0.f};
    f32x4 acc[4][4];
    #pragma unroll
    for (int ct = 0; ct < 4; ++ct)
        #pragma unroll
        for (int is = 0; is < 4; ++is) acc[ct][is] = z4;

    float lsum[4] = {0.f, 0.f, 0.f, 0.f};

    const unsigned short* Kb = Kt + (size_t)b * HW * 32;
    const unsigned short* Vw = Vb + ((size_t)b * CC + w * 64) * HW;

    for (int jt = 0; jt < NJT; ++jt) {
        const int j0 = jt * 64;

        // ---- QK^T (K frags from global, fully coalesced)
        f32x4 S[4];
        #pragma unroll
        for (int j2 = 0; j2 < 4; ++j2) {
            bf16x8 bk = *(const bf16x8*)(Kb + (size_t)(j0 + j2 * 16 + li) * 32 + lg * 8);
            S[j2] = __builtin_amdgcn_mfma_f32_16x16x32_bf16(aq, bk, z4, 0, 0, 0);
        }

        // ---- softmax numerator: p = exp2(s) (no max subtraction needed)
        unsigned int pk0[4], pk1[4];
        #pragma unroll
        for (int r = 0; r < 4; ++r) {
            float p0 = __builtin_amdgcn_exp2f(S[0][r]);
            float p1 = __builtin_amdgcn_exp2f(S[1][r]);
            float p2 = __builtin_amdgcn_exp2f(S[2][r]);
            float p3 = __builtin_amdgcn_exp2f(S[3][r]);
            lsum[r] += (p0 + p1) + (p2 + p3);
            asm("v_cvt_pk_bf16_f32 %0, %1, %2" : "=v"(pk0[r]) : "v"(p0), "v"(p1));
            asm("v_cvt_pk_bf16_f32 %0, %1, %2" : "=v"(pk1[r]) : "v"(p2), "v"(p3));
        }

        __syncthreads();  // prev tile's Ps reads complete
        #pragma unroll
        for (int r = 0; r < 4; ++r) {
            const int row = w * 16 + lg * 4 + r;
            Ps[row][li]      = (unsigned short)pk0[r];
            Ps[row][16 + li] = (unsigned short)(pk0[r] >> 16);
            Ps[row][32 + li] = (unsigned short)pk1[r];
            Ps[row][48 + li] = (unsigned short)(pk1[r] >> 16);
        }
        __syncthreads();  // Ps ready

        // ---- PV: V frags straight from global (L2), P from LDS
        bf16x8 bp[4][2];
        #pragma unroll
        for (int is = 0; is < 4; ++is)
            #pragma unroll
            for (int ks = 0; ks < 2; ++ks)
                bp[is][ks] = *(const bf16x8*)(&Ps[is * 16 + li][ks * 32 + lg * 8]);

        #pragma unroll
        for (int ct = 0; ct < 4; ++ct) {
            #pragma unroll
            for (int ks = 0; ks < 2; ++ks) {
                bf16x8 av = *(const bf16x8*)(
                    Vw + (size_t)(ct * 16 + li) * HW + j0 + ks * 32 + lg * 8);
                #pragma unroll
                for (int is = 0; is < 4; ++is)
                    acc[ct][is] = __builtin_amdgcn_mfma_f32_16x16x32_bf16(
                        av, bp[is][ks], acc[ct][is], 0, 0, 0);
            }
        }
    }

    // row-sum reduce over the 16 li lanes (j-distribution), once
    #pragma unroll
    for (int r = 0; r < 4; ++r) {
        float s = lsum[r];
        #pragma unroll
        for (int off = 1; off < 16; off <<= 1) s += __shfl_xor(s, off);
        if (li == 0) lls[w * 16 + lg * 4 + r] = s;
    }
    __syncthreads();

    float invl[4];
    #pragma unroll
    for (int is = 0; is < 4; ++is) invl[is] = 1.f / lls[is * 16 + li];

    #pragma unroll
    for (int ct = 0; ct < 4; ++ct)
        #pragma unroll
        for (int is = 0; is < 4; ++is)
            #pragma unroll
            for (int r = 0; r < 4; ++r) {
                int c = w * 64 + ct * 16 + lg * 4 + r;
                ATTb[((size_t)b * (4 * CC) + g * CC + c) * HW + i0 + is * 16 + li] =
                    f2bf(acc[ct][is][r] * invl[is]);
            }
}

// ---------------------------------------------------------------------------
// MFMA projection: out[b][co][i] = sum_{cin<1024} wproj[co][cin]*ATT[cin][i]+x.
// grid (HW/32, B), block 256 (4 waves, wave = 64-co strip).
// ---------------------------------------------------------------------------
__global__ __launch_bounds__(256) void gemm_proj(
    const unsigned short* __restrict__ ATTb, const unsigned short* __restrict__ Wpb,
    const float* __restrict__ x, float* __restrict__ out) {
    const int b = blockIdx.y;
    const int i0 = blockIdx.x * 32;
    const int t = threadIdx.x;
    const int lane = t & 63;
    const int w = t >> 6;
    const int lg = lane >> 4;
    const int li = lane & 15;

    __shared__ __align__(16) unsigned short As[32][72];  // [i][cin-chunk]

    const f32x4 z4 = (f32x4){0.f, 0.f, 0.f, 0.f};
    f32x4 acc[4][2];
    #pragma unroll
    for (int ct = 0; ct < 4; ++ct) { acc[ct][0] = z4; acc[ct][1] = z4; }

    for (int k0 = 0; k0 < 1024; k0 += 64) {
        __syncthreads();
        {
            int row = t >> 2, seg = t & 3;
            uint4 v = *(const uint4*)(
                ATTb + ((size_t)b * 1024 + k0 + row) * HW + i0 + seg * 8);
            const unsigned short* sv = (const unsigned short*)&v;
            #pragma unroll
            for (int u = 0; u < 8; ++u) As[seg * 8 + u][row] = sv[u];
        }
        __syncthreads();

        #pragma unroll
        for (int k2 = 0; k2 < 2; ++k2) {
            bf16x8 afr[2];
            #pragma unroll
            for (int is = 0; is < 2; ++is)
                afr[is] = *(const bf16x8*)(&As[is * 16 + li][k2 * 32 + lg * 8]);
            #pragma unroll
            for (int ct = 0; ct < 4; ++ct) {
                bf16x8 wf = *(const bf16x8*)(
                    Wpb + (size_t)(w * 64 + ct * 16 + li) * 1024 + k0 + k2 * 32 + lg * 8);
                #pragma unroll
                for (int is = 0; is < 2; ++is)
                    acc[ct][is] = __builtin_amdgcn_mfma_f32_16x16x32_bf16(
                        wf, afr[is], acc[ct][is], 0, 0, 0);
            }
        }
    }

    #pragma unroll
    for (int ct = 0; ct < 4; ++ct)
        #pragma unroll
        for (int is = 0; is < 2; ++is)
            #pragma unroll
            for (int r = 0; r < 4; ++r) {
                int co = w * 64 + ct * 16 + lg * 4 + r;
                size_t o = ((size_t)b * CC + co) * HW + i0 + is * 16 + li;
                out[o] = acc[ct][is][r] + x[o];
            }
}

// ---------------------------------------------------------------------------
// BatchNorm
// ---------------------------------------------------------------------------
__global__ __launch_bounds__(256) void bnstats(
    const float* __restrict__ out, float* __restrict__ mean,
    float* __restrict__ rstd) {
    const int c = blockIdx.x;
    float s = 0.f, s2 = 0.f;
    for (int e = threadIdx.x; e < BB * HW; e += 256) {
        int b = e / HW, i = e - b * HW;
        float v = out[((size_t)b * CC + c) * HW + i];
        s += v; s2 += v * v;
    }
    __shared__ float rs[256], rs2[256];
    rs[threadIdx.x] = s; rs2[threadIdx.x] = s2;
    __syncthreads();
    for (int st = 128; st > 0; st >>= 1) {
        if (threadIdx.x < st) {
            rs[threadIdx.x] += rs[threadIdx.x + st];
            rs2[threadIdx.x] += rs2[threadIdx.x + st];
        }
        __syncthreads();
    }
    if (threadIdx.x == 0) {
        const float n = (float)(BB * HW);
        float m = rs[0] / n;
        float var = rs2[0] / n - m * m;
        mean[c] = m;
        rstd[c] = rsqrtf(var + 1e-5f);
    }
}

__global__ __launch_bounds__(256) void bnapply(
    float* __restrict__ out, const float* __restrict__ mean,
    const float* __restrict__ rstd, const float* __restrict__ gamma,
    const float* __restrict__ beta) {
    size_t idx = (size_t)blockIdx.x * 256 + threadIdx.x;
    if (idx < (size_t)BB * CC * HW) {
        int c = (int)((idx / HW) % CC);
        out[idx] = (out[idx] - mean[c]) * rstd[c] * gamma[c] + beta[c];
    }
}

// ---------------------------------------------------------------------------
extern "C" void kernel_launch(void* const* d_in, const int* in_sizes, int n_in,
                              void* d_out, int out_size, void* d_ws, size_t ws_size,
                              hipStream_t stream) {
    const float* x     = (const float*)d_in[0];
    const float* wq1   = (const float*)d_in[1];
    const float* wq3   = (const float*)d_in[2];
    const float* wq5   = (const float*)d_in[3];
    const float* wq7   = (const float*)d_in[4];
    const float* wk    = (const float*)d_in[5];
    const float* wv    = (const float*)d_in[6];
    const float* wproj = (const float*)d_in[7];
    const float* gamma = (const float*)d_in[8];
    const float* beta  = (const float*)d_in[9];
    float* out = (float*)d_out;

    unsigned short* ATTb = (unsigned short*)d_ws;            // [B][1024][HW]
    unsigned short* Kt   = ATTb + (size_t)BB * 4 * CC * HW;  // [B][HW][32]
    unsigned short* Qt   = Kt + (size_t)BB * HW * 32;        // 4 x [B][HW][32]
    unsigned short* Vb   = Qt + (size_t)4 * BB * HW * 32;    // [B][C][HW]
    unsigned short* xT   = Vb + (size_t)BB * CC * HW;        // [B][HW][256]
    unsigned short* Wb3  = xT + (size_t)BB * HW * CC;        // [9][32][256]
    unsigned short* Wb5  = Wb3 + (size_t)9 * 32 * 256;
    unsigned short* Wb7  = Wb5 + (size_t)25 * 32 * 256;
    unsigned short* Wpb  = Wb7 + (size_t)49 * 32 * 256;      // [256][1024]
    unsigned short* Wkq  = Wpb + (size_t)256 * 1024;         // [2][32][256]
    unsigned short* Wvb  = Wkq + (size_t)2 * 32 * 256;       // [256][256]
    float* mean = (float*)(Wvb + (size_t)256 * 256);
    float* rstd = mean + CC;

    dim3 blk(256);

    // prep: all weights (one launch) + x transpose
    prep_weights<<<dim3(4000), blk, 0, stream>>>(
        wq3, wq5, wq7, wproj, wk, wq1, wv, Wb3, Wb5, Wb7, Wpb, Wkq, Wvb);
    transpose_x<<<dim3(HW / 32, CC / 32, BB), blk, 0, stream>>>(x, xT);

    // K + Q1 (MFMA, no LDS), V (MFMA, no LDS)
    qk32_mfma<<<dim3(HW / 64, BB, 2), blk, 0, stream>>>(xT, Wkq, Kt, Qt);
    v_mfma<<<dim3(HW / 32, BB), blk, 0, stream>>>(xT, Wvb, Vb);

    // q3/q5/q7 fused MFMA im2col convs
    qconv_all<<<dim3(HW / 64, BB, 3), blk, 0, stream>>>(xT, Wb3, Wb5, Wb7, Qt);

    // MFMA flash attention (round-6 verified version), all 4 branches
    flashmfma<<<dim3(HW / 64, BB, 4), blk, 0, stream>>>(Qt, Kt, Vb, ATTb);

    // MFMA projection + residual -> d_out (pre-BN, fp32)
    gemm_proj<<<dim3(HW / 32, BB), blk, 0, stream>>>(ATTb, Wpb, x, out);

    // BatchNorm
    bnstats<<<dim3(CC), blk, 0, stream>>>(out, mean, rstd);
    bnapply<<<dim3((BB * CC * HW + 255) / 256), blk, 0, stream>>>(out, mean, rstd, gamma, beta);
}

// Round 11
// 480.106 us; speedup vs baseline: 125.3424x; 1.0305x over previous
//
#include <hip/hip_runtime.h>
#include <hip/hip_bf16.h>
#include <math.h>

#define HW 3136
#define WIDTH 56
#define CC 256
#define BB 4
#define RCH 32
#define NJT (HW / 64)
#define SCLOG2E 0.2550437041556575f  // (1/sqrt(32)) * log2(e), folded into Q

using bf16x8 = __attribute__((ext_vector_type(8))) short;
using f32x4  = __attribute__((ext_vector_type(4))) float;

static __device__ __forceinline__ unsigned short f2bf(float f) {
    __hip_bfloat16 h = __float2bfloat16(f);
    return *reinterpret_cast<unsigned short*>(&h);
}

// ---------------------------------------------------------------------------
// Fused weight prep: q-conv repacks (Wb[t][r][c]), wproj cast, wk/wq1 cast,
// wv cast. One launch.
// ---------------------------------------------------------------------------
__global__ __launch_bounds__(256) void prep_weights(
    const float* __restrict__ wq3, const float* __restrict__ wq5,
    const float* __restrict__ wq7, const float* __restrict__ wproj,
    const float* __restrict__ wk, const float* __restrict__ wq1,
    const float* __restrict__ wv,
    unsigned short* __restrict__ Wb3, unsigned short* __restrict__ Wb5,
    unsigned short* __restrict__ Wb7, unsigned short* __restrict__ Wpb,
    unsigned short* __restrict__ Wkq, unsigned short* __restrict__ Wvb) {
    int e = blockIdx.x * 256 + threadIdx.x;
    if (e < 73728) {  // wq3: KT=9
        int c = e & 255, r = (e >> 8) & 31, t = e >> 13;
        Wb3[e] = f2bf(wq3[((size_t)r * 256 + c) * 9 + t]);
    } else if (e < 278528) {  // wq5: KT=25
        int i = e - 73728;
        int c = i & 255, r = (i >> 8) & 31, t = i >> 13;
        Wb5[i] = f2bf(wq5[((size_t)r * 256 + c) * 25 + t]);
    } else if (e < 679936) {  // wq7: KT=49
        int i = e - 278528;
        int c = i & 255, r = (i >> 8) & 31, t = i >> 13;
        Wb7[i] = f2bf(wq7[((size_t)r * 256 + c) * 49 + t]);
    } else if (e < 942080) {  // wproj [256][1024]
        int i = e - 679936;
        Wpb[i] = f2bf(wproj[i]);
    } else if (e < 958464) {  // wk | wq1, [2][32][256]
        int i = e - 942080;
        Wkq[i] = f2bf(i < 8192 ? wk[i] : wq1[i - 8192]);
    } else if (e < 1024000) {  // wv [256][256]
        int i = e - 958464;
        Wvb[i] = f2bf(wv[i]);
    }
}

// ---------------------------------------------------------------------------
// x transpose + bf16: xT[b][hw][c]. grid (HW/32, C/32, B), block 256 (32x8).
// ---------------------------------------------------------------------------
__global__ __launch_bounds__(256) void transpose_x(
    const float* __restrict__ x, unsigned short* __restrict__ xT) {
    __shared__ unsigned short tile[32][33];
    const int b = blockIdx.z;
    const int i0 = blockIdx.x * 32, c0 = blockIdx.y * 32;
    const int tx = threadIdx.x & 31, ty = threadIdx.x >> 5;
    #pragma unroll
    for (int k = 0; k < 4; ++k)
        tile[ty + k * 8][tx] = f2bf(x[((size_t)b * CC + c0 + ty + k * 8) * HW + i0 + tx]);
    __syncthreads();
    #pragma unroll
    for (int k = 0; k < 4; ++k)
        xT[((size_t)b * HW + i0 + ty + k * 8) * 256 + c0 + tx] = tile[tx][ty + k * 8];
}

// ---------------------------------------------------------------------------
// K / Q1 via MFMA, no LDS, no barriers. outt[b][hw][32] bf16 (Q pre-scaled).
// grid (HW/64, B, 2): z=0 -> K (scale 1), z=1 -> Q1 (scale SCLOG2E).
// ---------------------------------------------------------------------------
__global__ __launch_bounds__(256) void qk32_mfma(
    const unsigned short* __restrict__ xT, const unsigned short* __restrict__ Wkq,
    unsigned short* __restrict__ Kt, unsigned short* __restrict__ Qt) {
    const int b = blockIdx.y, z = blockIdx.z;
    const int i0 = blockIdx.x * 64;
    const int t = threadIdx.x;
    const int lane = t & 63, w = t >> 6, lg = lane >> 4, li = lane & 15;

    unsigned short* outp = z == 0 ? Kt : Qt;
    const float osc = z == 0 ? 1.0f : SCLOG2E;
    const unsigned short* wb = Wkq + z * 8192;
    const unsigned short* xb = xT + ((size_t)b * HW + i0 + w * 16 + li) * 256;

    const f32x4 z4 = (f32x4){0.f, 0.f, 0.f, 0.f};
    f32x4 acc[2] = {z4, z4};

    for (int c0 = 0; c0 < 256; c0 += 32) {
        bf16x8 ax = *(const bf16x8*)(xb + c0 + lg * 8);
        #pragma unroll
        for (int rs = 0; rs < 2; ++rs) {
            bf16x8 bw = *(const bf16x8*)(wb + (size_t)(rs * 16 + li) * 256 + c0 + lg * 8);
            acc[rs] = __builtin_amdgcn_mfma_f32_16x16x32_bf16(ax, bw, acc[rs], 0, 0, 0);
        }
    }
    unsigned short* qb = outp + ((size_t)b * HW + i0 + w * 16 + lg * 4) * 32;
    #pragma unroll
    for (int rs = 0; rs < 2; ++rs)
        #pragma unroll
        for (int r = 0; r < 4; ++r)
            qb[(size_t)r * 32 + rs * 16 + li] = f2bf(acc[rs][r] * osc);
}

// ---------------------------------------------------------------------------
// V via MFMA, no LDS, no barriers. V[b][co][hw] bf16.
// grid (HW/32, B). Wave w owns co strip w*64..+63.
// ---------------------------------------------------------------------------
__global__ __launch_bounds__(256) void v_mfma(
    const unsigned short* __restrict__ xT, const unsigned short* __restrict__ Wvb,
    unsigned short* __restrict__ Vb) {
    const int b = blockIdx.y;
    const int i0 = blockIdx.x * 32;
    const int t = threadIdx.x;
    const int lane = t & 63, w = t >> 6, lg = lane >> 4, li = lane & 15;

    const f32x4 z4 = (f32x4){0.f, 0.f, 0.f, 0.f};
    f32x4 acc[4][2];
    #pragma unroll
    for (int ct = 0; ct < 4; ++ct) { acc[ct][0] = z4; acc[ct][1] = z4; }

    const unsigned short* xb = xT + (size_t)b * HW * 256;

    for (int c0 = 0; c0 < 256; c0 += 32) {
        bf16x8 bx[2];
        #pragma unroll
        for (int is = 0; is < 2; ++is)
            bx[is] = *(const bf16x8*)(xb + (size_t)(i0 + is * 16 + li) * 256 + c0 + lg * 8);
        #pragma unroll
        for (int ct = 0; ct < 4; ++ct) {
            bf16x8 aw = *(const bf16x8*)(
                Wvb + (size_t)(w * 64 + ct * 16 + li) * 256 + c0 + lg * 8);
            #pragma unroll
            for (int is = 0; is < 2; ++is)
                acc[ct][is] = __builtin_amdgcn_mfma_f32_16x16x32_bf16(
                    aw, bx[is], acc[ct][is], 0, 0, 0);
        }
    }
    #pragma unroll
    for (int ct = 0; ct < 4; ++ct)
        #pragma unroll
        for (int is = 0; is < 2; ++is)
            #pragma unroll
            for (int r = 0; r < 4; ++r)
                Vb[((size_t)b * CC + w * 64 + ct * 16 + lg * 4 + r) * HW +
                   i0 + is * 16 + li] = f2bf(acc[ct][is][r]);
}

// ---------------------------------------------------------------------------
// MFMA im2col q-conv body (shared LDS passed in). Output scaled by SCLOG2E.
// ---------------------------------------------------------------------------
template <int KS>
static __device__ __forceinline__ void qconv_body(
    const unsigned short* __restrict__ xT,  // [b][hw][256] bf16
    const unsigned short* __restrict__ Wb,  // [KT][32][256] bf16
    unsigned short* __restrict__ q,         // [b][hw][32] bf16
    unsigned short (*xs)[40]) {
    constexpr int P = (KS - 1) / 2;
    constexpr int KT = KS * KS;
    constexpr int ROWS = 64 + 114 * P;
    const int b = blockIdx.y;
    const int i0 = blockIdx.x * 64;
    const int t = threadIdx.x;
    const int lane = t & 63;
    const int w = t >> 6;
    const int li = lane & 15;
    const int lg = lane >> 4;

    const int base = i0 - P * 57;
    const int mycol = (i0 + w * 16 + li) % WIDTH;

    f32x4 acc[2];
    acc[0] = (f32x4){0.f, 0.f, 0.f, 0.f};
    acc[1] = (f32x4){0.f, 0.f, 0.f, 0.f};

    const unsigned short* xTb = xT + (size_t)b * HW * 256;

    for (int c0 = 0; c0 < 256; c0 += 32) {
        __syncthreads();
        for (int e = t; e < ROWS * 4; e += 256) {
            int row = e >> 2, cs = e & 3;
            int gidx = base + row;
            uint4 val = make_uint4(0, 0, 0, 0);
            if (gidx >= 0 && gidx < HW)
                val = *(const uint4*)(xTb + (size_t)gidx * 256 + c0 + cs * 8);
            *(uint4*)(&xs[row][cs * 8]) = val;
        }
        __syncthreads();

        #pragma unroll
        for (int tap = 0; tap < KT; ++tap) {
            const int dx = tap % KS - P;
            const int poff = (tap / KS) * WIDTH + tap % KS;
            bf16x8 a = *(const bf16x8*)(&xs[w * 16 + li + poff][lg * 8]);
            if ((unsigned)(mycol + dx) >= (unsigned)WIDTH)
                a = (bf16x8){0, 0, 0, 0, 0, 0, 0, 0};
            const unsigned short* wrow =
                Wb + (size_t)tap * 32 * 256 + c0 + lg * 8;
            bf16x8 b0 = *(const bf16x8*)(wrow + (size_t)li * 256);
            bf16x8 b1 = *(const bf16x8*)(wrow + (size_t)(16 + li) * 256);
            acc[0] = __builtin_amdgcn_mfma_f32_16x16x32_bf16(a, b0, acc[0], 0, 0, 0);
            acc[1] = __builtin_amdgcn_mfma_f32_16x16x32_bf16(a, b1, acc[1], 0, 0, 0);
        }
    }

    unsigned short* qb = q + ((size_t)b * HW + i0 + w * 16 + lg * 4) * 32;
    #pragma unroll
    for (int rs = 0; rs < 2; ++rs)
        #pragma unroll
        for (int r = 0; r < 4; ++r)
            qb[(size_t)r * 32 + rs * 16 + li] = f2bf(acc[rs][r] * SCLOG2E);
}

// All three q-convs in one launch: grid (HW/64, B, 3), z picks kernel size.
__global__ __launch_bounds__(256) void qconv_all(
    const unsigned short* __restrict__ xT,
    const unsigned short* __restrict__ Wb3,
    const unsigned short* __restrict__ Wb5,
    const unsigned short* __restrict__ Wb7,
    unsigned short* __restrict__ Qt) {
    __shared__ unsigned short xs[406][40];  // sized for KS=7
    const size_t QSLICE = (size_t)BB * HW * 32;
    if (blockIdx.z == 0)      qconv_body<3>(xT, Wb3, Qt + 1 * QSLICE, xs);
    else if (blockIdx.z == 1) qconv_body<5>(xT, Wb5, Qt + 2 * QSLICE, xs);
    else                      qconv_body<7>(xT, Wb7, Qt + 3 * QSLICE, xs);
}

// ---------------------------------------------------------------------------
// MFMA flash attention — round-6/9 sync structure VERBATIM (single Ps buffer,
// two barriers per tile, no cross-iteration register carrying). One change:
// the 8 V fragment loads for the CURRENT tile are issued at the TOP of the
// iteration (before QK) instead of after the second barrier, so their L2
// latency is covered by QK + softmax + barriers. Same iteration, same
// addresses, pure code motion; LLVM cannot sink loads across __syncthreads.
// grid: (HW/64, B, 4), block 256 (4 waves).
// ---------------------------------------------------------------------------
__global__ __launch_bounds__(256) void flashmfma(
    const unsigned short* __restrict__ Qt, const unsigned short* __restrict__ Kt,
    const unsigned short* __restrict__ Vb, unsigned short* __restrict__ ATTb) {
    const int b = blockIdx.y, g = blockIdx.z;
    const int i0 = blockIdx.x * 64;
    const int t = threadIdx.x;
    const int lane = t & 63;
    const int w = t >> 6;
    const int lg = lane >> 4;
    const int li = lane & 15;

    __shared__ __align__(16) unsigned short Ps[64][72];  // 144B rows (16B mult)
    __shared__ float lls[64];

    // Q fragment for this wave's i-strip, loop-invariant (Q pre-scaled)
    const bf16x8 aq = *(const bf16x8*)(
        Qt + ((size_t)(g * BB + b) * HW + i0 + w * 16 + li) * 32 + lg * 8);

    const f32x4 z4 = (f32x4){0.f, 0.f, 0.f, 0.f};
    f32x4 acc[4][4];
    #pragma unroll
    for (int ct = 0; ct < 4; ++ct)
        #pragma unroll
        for (int is = 0; is < 4; ++is) acc[ct][is] = z4;

    float lsum[4] = {0.f, 0.f, 0.f, 0.f};

    const unsigned short* Kb = Kt + (size_t)b * HW * 32;
    const unsigned short* Vw = Vb + ((size_t)b * CC + w * 64) * HW;

    for (int jt = 0; jt < NJT; ++jt) {
        const int j0 = jt * 64;

        // ---- issue THIS tile's V fragment loads first (consumed after the
        // barriers in PV; latency hidden under QK + softmax)
        bf16x8 vf[4][2];
        #pragma unroll
        for (int ct = 0; ct < 4; ++ct) {
            vf[ct][0] = *(const bf16x8*)(
                Vw + (size_t)(ct * 16 + li) * HW + j0 + lg * 8);
            vf[ct][1] = *(const bf16x8*)(
                Vw + (size_t)(ct * 16 + li) * HW + j0 + 32 + lg * 8);
        }

        // ---- QK^T (K frags from global, fully coalesced)
        f32x4 S[4];
        #pragma unroll
        for (int j2 = 0; j2 < 4; ++j2) {
            bf16x8 bk = *(const bf16x8*)(Kb + (size_t)(j0 + j2 * 16 + li) * 32 + lg * 8);
            S[j2] = __builtin_amdgcn_mfma_f32_16x16x32_bf16(aq, bk, z4, 0, 0, 0);
        }

        // ---- softmax numerator: p = exp2(s) (no max subtraction needed)
        unsigned int pk0[4], pk1[4];
        #pragma unroll
        for (int r = 0; r < 4; ++r) {
            float p0 = __builtin_amdgcn_exp2f(S[0][r]);
            float p1 = __builtin_amdgcn_exp2f(S[1][r]);
            float p2 = __builtin_amdgcn_exp2f(S[2][r]);
            float p3 = __builtin_amdgcn_exp2f(S[3][r]);
            lsum[r] += (p0 + p1) + (p2 + p3);
            asm("v_cvt_pk_bf16_f32 %0, %1, %2" : "=v"(pk0[r]) : "v"(p0), "v"(p1));
            asm("v_cvt_pk_bf16_f32 %0, %1, %2" : "=v"(pk1[r]) : "v"(p2), "v"(p3));
        }

        __syncthreads();  // prev tile's Ps reads complete
        #pragma unroll
        for (int r = 0; r < 4; ++r) {
            const int row = w * 16 + lg * 4 + r;
            Ps[row][li]      = (unsigned short)pk0[r];
            Ps[row][16 + li] = (unsigned short)(pk0[r] >> 16);
            Ps[row][32 + li] = (unsigned short)pk1[r];
            Ps[row][48 + li] = (unsigned short)(pk1[r] >> 16);
        }
        __syncthreads();  // Ps ready

        // ---- PV: V from the fragments issued at loop top, P from LDS
        bf16x8 bp[4][2];
        #pragma unroll
        for (int is = 0; is < 4; ++is)
            #pragma unroll
            for (int ks = 0; ks < 2; ++ks)
                bp[is][ks] = *(const bf16x8*)(&Ps[is * 16 + li][ks * 32 + lg * 8]);

        #pragma unroll
        for (int ct = 0; ct < 4; ++ct) {
            #pragma unroll
            for (int is = 0; is < 4; ++is) {
                acc[ct][is] = __builtin_amdgcn_mfma_f32_16x16x32_bf16(
                    vf[ct][0], bp[is][0], acc[ct][is], 0, 0, 0);
                acc[ct][is] = __builtin_amdgcn_mfma_f32_16x16x32_bf16(
                    vf[ct][1], bp[is][1], acc[ct][is], 0, 0, 0);
            }
        }
    }

    // row-sum reduce over the 16 li lanes (j-distribution), once
    #pragma unroll
    for (int r = 0; r < 4; ++r) {
        float s = lsum[r];
        #pragma unroll
        for (int off = 1; off < 16; off <<= 1) s += __shfl_xor(s, off);
        if (li == 0) lls[w * 16 + lg * 4 + r] = s;
    }
    __syncthreads();

    float invl[4];
    #pragma unroll
    for (int is = 0; is < 4; ++is) invl[is] = 1.f / lls[is * 16 + li];

    #pragma unroll
    for (int ct = 0; ct < 4; ++ct)
        #pragma unroll
        for (int is = 0; is < 4; ++is)
            #pragma unroll
            for (int r = 0; r < 4; ++r) {
                int c = w * 64 + ct * 16 + lg * 4 + r;
                ATTb[((size_t)b * (4 * CC) + g * CC + c) * HW + i0 + is * 16 + li] =
                    f2bf(acc[ct][is][r] * invl[is]);
            }
}

// ---------------------------------------------------------------------------
// MFMA projection: out[b][co][i] = sum_{cin<1024} wproj[co][cin]*ATT[cin][i]+x.
// grid (HW/32, B), block 256 (4 waves, wave = 64-co strip).
// ---------------------------------------------------------------------------
__global__ __launch_bounds__(256) void gemm_proj(
    const unsigned short* __restrict__ ATTb, const unsigned short* __restrict__ Wpb,
    const float* __restrict__ x, float* __restrict__ out) {
    const int b = blockIdx.y;
    const int i0 = blockIdx.x * 32;
    const int t = threadIdx.x;
    const int lane = t & 63;
    const int w = t >> 6;
    const int lg = lane >> 4;
    const int li = lane & 15;

    __shared__ __align__(16) unsigned short As[32][72];  // [i][cin-chunk]

    const f32x4 z4 = (f32x4){0.f, 0.f, 0.f, 0.f};
    f32x4 acc[4][2];
    #pragma unroll
    for (int ct = 0; ct < 4; ++ct) { acc[ct][0] = z4; acc[ct][1] = z4; }

    for (int k0 = 0; k0 < 1024; k0 += 64) {
        __syncthreads();
        {
            int row = t >> 2, seg = t & 3;
            uint4 v = *(const uint4*)(
                ATTb + ((size_t)b * 1024 + k0 + row) * HW + i0 + seg * 8);
            const unsigned short* sv = (const unsigned short*)&v;
            #pragma unroll
            for (int u = 0; u < 8; ++u) As[seg * 8 + u][row] = sv[u];
        }
        __syncthreads();

        #pragma unroll
        for (int k2 = 0; k2 < 2; ++k2) {
            bf16x8 afr[2];
            #pragma unroll
            for (int is = 0; is < 2; ++is)
                afr[is] = *(const bf16x8*)(&As[is * 16 + li][k2 * 32 + lg * 8]);
            #pragma unroll
            for (int ct = 0; ct < 4; ++ct) {
                bf16x8 wf = *(const bf16x8*)(
                    Wpb + (size_t)(w * 64 + ct * 16 + li) * 1024 + k0 + k2 * 32 + lg * 8);
                #pragma unroll
                for (int is = 0; is < 2; ++is)
                    acc[ct][is] = __builtin_amdgcn_mfma_f32_16x16x32_bf16(
                        wf, afr[is], acc[ct][is], 0, 0, 0);
            }
        }
    }

    #pragma unroll
    for (int ct = 0; ct < 4; ++ct)
        #pragma unroll
        for (int is = 0; is < 2; ++is)
            #pragma unroll
            for (int r = 0; r < 4; ++r) {
                int co = w * 64 + ct * 16 + lg * 4 + r;
                size_t o = ((size_t)b * CC + co) * HW + i0 + is * 16 + li;
                out[o] = acc[ct][is][r] + x[o];
            }
}

// ---------------------------------------------------------------------------
// BatchNorm
// ---------------------------------------------------------------------------
__global__ __launch_bounds__(256) void bnstats(
    const float* __restrict__ out, float* __restrict__ mean,
    float* __restrict__ rstd) {
    const int c = blockIdx.x;
    float s = 0.f, s2 = 0.f;
    for (int e = threadIdx.x; e < BB * HW; e += 256) {
        int b = e / HW, i = e - b * HW;
        float v = out[((size_t)b * CC + c) * HW + i];
        s += v; s2 += v * v;
    }
    __shared__ float rs[256], rs2[256];
    rs[threadIdx.x] = s; rs2[threadIdx.x] = s2;
    __syncthreads();
    for (int st = 128; st > 0; st >>= 1) {
        if (threadIdx.x < st) {
            rs[threadIdx.x] += rs[threadIdx.x + st];
            rs2[threadIdx.x] += rs2[threadIdx.x + st];
        }
        __syncthreads();
    }
    if (threadIdx.x == 0) {
        const float n = (float)(BB * HW);
        float m = rs[0] / n;
        float var = rs2[0] / n - m * m;
        mean[c] = m;
        rstd[c] = rsqrtf(var + 1e-5f);
    }
}

__global__ __launch_bounds__(256) void bnapply(
    float* __restrict__ out, const float* __restrict__ mean,
    const float* __restrict__ rstd, const float* __restrict__ gamma,
    const float* __restrict__ beta) {
    size_t idx = (size_t)blockIdx.x * 256 + threadIdx.x;
    if (idx < (size_t)BB * CC * HW) {
        int c = (int)((idx / HW) % CC);
        out[idx] = (out[idx] - mean[c]) * rstd[c] * gamma[c] + beta[c];
    }
}

// ---------------------------------------------------------------------------
extern "C" void kernel_launch(void* const* d_in, const int* in_sizes, int n_in,
                              void* d_out, int out_size, void* d_ws, size_t ws_size,
                              hipStream_t stream) {
    const float* x     = (const float*)d_in[0];
    const float* wq1   = (const float*)d_in[1];
    const float* wq3   = (const float*)d_in[2];
    const float* wq5   = (const float*)d_in[3];
    const float* wq7   = (const float*)d_in[4];
    const float* wk    = (const float*)d_in[5];
    const float* wv    = (const float*)d_in[6];
    const float* wproj = (const float*)d_in[7];
    const float* gamma = (const float*)d_in[8];
    const float* beta  = (const float*)d_in[9];
    float* out = (float*)d_out;

    unsigned short* ATTb = (unsigned short*)d_ws;            // [B][1024][HW]
    unsigned short* Kt   = ATTb + (size_t)BB * 4 * CC * HW;  // [B][HW][32]
    unsigned short* Qt   = Kt + (size_t)BB * HW * 32;        // 4 x [B][HW][32]
    unsigned short* Vb   = Qt + (size_t)4 * BB * HW * 32;    // [B][C][HW]
    unsigned short* xT   = Vb + (size_t)BB * CC * HW;        // [B][HW][256]
    unsigned short* Wb3  = xT + (size_t)BB * HW * CC;        // [9][32][256]
    unsigned short* Wb5  = Wb3 + (size_t)9 * 32 * 256;
    unsigned short* Wb7  = Wb5 + (size_t)25 * 32 * 256;
    unsigned short* Wpb  = Wb7 + (size_t)49 * 32 * 256;      // [256][1024]
    unsigned short* Wkq  = Wpb + (size_t)256 * 1024;         // [2][32][256]
    unsigned short* Wvb  = Wkq + (size_t)2 * 32 * 256;       // [256][256]
    float* mean = (float*)(Wvb + (size_t)256 * 256);
    float* rstd = mean + CC;

    dim3 blk(256);

    // prep: all weights (one launch) + x transpose
    prep_weights<<<dim3(4000), blk, 0, stream>>>(
        wq3, wq5, wq7, wproj, wk, wq1, wv, Wb3, Wb5, Wb7, Wpb, Wkq, Wvb);
    transpose_x<<<dim3(HW / 32, CC / 32, BB), blk, 0, stream>>>(x, xT);

    // K + Q1 (MFMA, no LDS), V (MFMA, no LDS)
    qk32_mfma<<<dim3(HW / 64, BB, 2), blk, 0, stream>>>(xT, Wkq, Kt, Qt);
    v_mfma<<<dim3(HW / 32, BB), blk, 0, stream>>>(xT, Wvb, Vb);

    // q3/q5/q7 fused MFMA im2col convs
    qconv_all<<<dim3(HW / 64, BB, 3), blk, 0, stream>>>(xT, Wb3, Wb5, Wb7, Qt);

    // MFMA flash attention (round-9 sync structure + within-iteration V hoist)
    flashmfma<<<dim3(HW / 64, BB, 4), blk, 0, stream>>>(Qt, Kt, Vb, ATTb);

    // MFMA projection + residual -> d_out (pre-BN, fp32)
    gemm_proj<<<dim3(HW / 32, BB), blk, 0, stream>>>(ATTb, Wpb, x, out);

    // BatchNorm
    bnstats<<<dim3(CC), blk, 0, stream>>>(out, mean, rstd);
    bnapply<<<dim3((BB * CC * HW + 255) / 256), blk, 0, stream>>>(out, mean, rstd, gamma, beta);
}